// Round 2
// baseline (3043.228 us; speedup 1.0000x reference)
//
#include <hip/hip_runtime.h>
#include <hip/hip_bf16.h>

typedef __bf16 bf16;
typedef __attribute__((ext_vector_type(8))) __bf16 bf16x8;
typedef __attribute__((ext_vector_type(4))) __bf16 bf16x4;
typedef __attribute__((ext_vector_type(4))) float f32x4;

#define TOKENS 15360   // B*S = 16*960
#define HID    512
#define FFN_D  2048
#define QKV_D  1536

// ---------------------------------------------------------------------------
// fast exact-GELU: A&S 7.1.26 erf (|eps|<=1.5e-7), hw exp + hw rcp
// ---------------------------------------------------------------------------
__device__ __forceinline__ float gelu_erf(float x) {
  const float z = fabsf(x) * 0.70710678118654752f;
#if __has_builtin(__builtin_amdgcn_rcpf)
  const float t = __builtin_amdgcn_rcpf(fmaf(0.3275911f, z, 1.f));
#else
  const float t = 1.f / fmaf(0.3275911f, z, 1.f);
#endif
  float p = fmaf(1.061405429f, t, -1.453152027f);
  p = fmaf(p, t, 1.421413741f);
  p = fmaf(p, t, -0.284496736f);
  p = fmaf(p, t, 0.254829592f);
  p *= t;
  const float e  = __expf(-z * z);
  const float er = fmaf(-p, e, 1.f);          // erf(|x|/sqrt2)
  return 0.5f * x * (1.f + copysignf(er, x));
}

// ---------------------------------------------------------------------------
// fp32 -> bf16 weight conversion (run every launch; ws is re-poisoned)
// ---------------------------------------------------------------------------
__global__ __launch_bounds__(256) void cvt_kernel(const float* __restrict__ src,
                                                  bf16* __restrict__ dst, int n4) {
  const int i = (blockIdx.x * 256 + threadIdx.x);
  if (i >= n4) return;
  const float4 v = ((const float4*)src)[i];
  bf16x4 d = {(bf16)v.x, (bf16)v.y, (bf16)v.z, (bf16)v.w};
  *(bf16x4*)(dst + (size_t)i * 4) = d;
}

// W2 [4][512][2048] fp32 -> split bf16 [4][2][512][1024]:
// dst[l][h][n][c] = src[l][n][h*1024+c]  (so each K=1024 half has contiguous rows)
__global__ __launch_bounds__(256) void cvt_w2_kernel(const float* __restrict__ src,
                                                     bf16* __restrict__ dst, int n4) {
  const int i = (blockIdx.x * 256 + threadIdx.x);
  if (i >= n4) return;
  const int f  = i * 4;
  const int ln = f >> 11;        // l*512 + n
  const int c2 = f & 2047;
  const int h  = c2 >> 10;
  const int c  = c2 & 1023;
  const int l  = ln >> 9;
  const int n  = ln & 511;
  const float4 v = ((const float4*)src)[i];
  bf16x4 d = {(bf16)v.x, (bf16)v.y, (bf16)v.z, (bf16)v.w};
  *(bf16x4*)(dst + ((((size_t)(l * 2 + h) * 512 + n) << 10) + c)) = d;
}

// ---------------------------------------------------------------------------
// GEMM: C[M,N] = A[M,K] @ W[N,K]^T (+bias fp32, + optional residual / GELU /
// fp32-accumulate).
// BM=256, BN=128, BK=64, 512 threads = 8 waves (4M x 2N), each wave 64x64 via
// 4x4 mfma_f32_16x16x32_bf16. TRIPLE-buffered LDS (144 KB), prefetch distance
// 2 K-tiles, ONE barrier per K-tile, counted vmcnt(6) (= tile t+1's 6 loads
// stay in flight; in-order VMEM retirement => tile t has landed). Only the
// last K-tile drains vmcnt(0). setprio(1) wraps each MFMA cluster.
// Sync audit: buf (t+2)%3 is written only after the iter-t barrier, which all
// waves reach only after finishing reads of that buf in iter t-1; reads of
// buf t%3 never alias in-flight writes (those target bufs (t+1)%3,(t+2)%3).
// XOR swizzle (slot s holds k-chunk s^(r&7)) keeps global_load_lds linear-dest
// contiguity AND makes ds_read_b128 conflict-free (measured 0).
// ---------------------------------------------------------------------------
#define EPI_BIAS_BF16     0
#define EPI_BIAS_RES_F32  1
#define EPI_BIAS_GELU     2
#define EPI_ACC_F32       3   // out(fp32) += acc  (no bias, no residual)

template <int EPI>
__global__ __launch_bounds__(512, 2) void gemm_bt(
    const bf16* __restrict__ A, const bf16* __restrict__ W,
    const float* __restrict__ bias, const bf16* __restrict__ R,
    void* __restrict__ out, int M, int N, int K) {
  __shared__ __align__(16) bf16 As[3 * 256 * 64];   // 96 KB
  __shared__ __align__(16) bf16 Bs[3 * 128 * 64];   // 48 KB

  const int tid  = threadIdx.x;
  const int lane = tid & 63;
  const int wv   = tid >> 6;
  const int li   = lane & 15;
  const int qd   = lane >> 4;
  const int mw   = (wv & 3) << 6;    // 4 m-tiles of 64
  const int nw   = (wv >> 2) << 6;   // 2 n-tiles of 64

  // XCD-chunked block swizzle (bijective since nwg % 8 == 0 for all shapes)
  const int gx  = gridDim.x;
  const int nwg = gx * gridDim.y;
  int lid = blockIdx.y * gx + blockIdx.x;
  if ((nwg & 7) == 0) lid = (lid & 7) * (nwg >> 3) + (lid >> 3);
  const int m0 = (lid % gx) << 8;
  const int n0 = (lid / gx) << 7;

  f32x4 acc[4][4];
#pragma unroll
  for (int i = 0; i < 4; ++i)
#pragma unroll
    for (int j = 0; j < 4; ++j) acc[i][j] = (f32x4){0.f, 0.f, 0.f, 0.f};

  // staging: A tile 256x64 = 2048 16B-chunks (4 loads/thread), B tile 128x64
  // = 1024 chunks (2 loads/thread). chunk q -> row r=q>>3, slot s=q&7; source
  // k-chunk = s^(r&7) (pre-swizzled source, linear LDS dest).
  const bf16* pa[4];
  const bf16* pb[2];
  int oa[4], ob[2];
#pragma unroll
  for (int l = 0; l < 4; ++l) {
    const int q = l * 512 + tid;
    const int r = q >> 3, s = q & 7;
    pa[l] = A + (size_t)(m0 + r) * K + ((s ^ (r & 7)) << 3);
    oa[l] = (l * 512 + (tid & 448)) << 3;   // wave-uniform LDS base (elems)
  }
#pragma unroll
  for (int l = 0; l < 2; ++l) {
    const int q = l * 512 + tid;
    const int r = q >> 3, s = q & 7;
    pb[l] = W + (size_t)(n0 + r) * K + ((s ^ (r & 7)) << 3);
    ob[l] = (l * 512 + (tid & 448)) << 3;
  }

  auto stage = [&](int buf) {   // 6 global_load_lds per thread (4 A + 2 B)
#pragma unroll
    for (int l = 0; l < 4; ++l) {
      __builtin_amdgcn_global_load_lds(
          (const __attribute__((address_space(1))) unsigned int*)pa[l],
          (__attribute__((address_space(3))) unsigned int*)(As + buf * 16384 + oa[l]),
          16, 0, 0);
      pa[l] += 64;
    }
#pragma unroll
    for (int l = 0; l < 2; ++l) {
      __builtin_amdgcn_global_load_lds(
          (const __attribute__((address_space(1))) unsigned int*)pb[l],
          (__attribute__((address_space(3))) unsigned int*)(Bs + buf * 8192 + ob[l]),
          16, 0, 0);
      pb[l] += 64;
    }
  };

  auto compute = [&](int buf) {
    const bf16* Ab = As + buf * 16384;
    const bf16* Bb = Bs + buf * 8192;
#pragma unroll
    for (int ks = 0; ks < 2; ++ks) {
      const int ck = (ks << 2) + qd;
      const int sl = (ck ^ (li & 7)) << 3;   // frag-row&7 == li&7 (rows = x*16+li)
      bf16x8 af[4], bfv[4];
#pragma unroll
      for (int i = 0; i < 4; ++i)
        af[i] = *(const bf16x8*)(Ab + (mw + i * 16 + li) * 64 + sl);
#pragma unroll
      for (int j = 0; j < 4; ++j)
        bfv[j] = *(const bf16x8*)(Bb + (nw + j * 16 + li) * 64 + sl);
      __builtin_amdgcn_s_setprio(1);
#pragma unroll
      for (int i = 0; i < 4; ++i)
#pragma unroll
        for (int j = 0; j < 4; ++j)
          acc[i][j] = __builtin_amdgcn_mfma_f32_16x16x32_bf16(af[i], bfv[j],
                                                              acc[i][j], 0, 0, 0);
      __builtin_amdgcn_s_setprio(0);
    }
  };

  const int nt = K >> 6;   // 8 or 16 for all our shapes
  stage(0);
  stage(1);
  for (int t = 0; t < nt; ++t) {
    if (t + 1 < nt) asm volatile("s_waitcnt vmcnt(6)" ::: "memory");
    else            asm volatile("s_waitcnt vmcnt(0)" ::: "memory");
    __builtin_amdgcn_s_barrier();
    asm volatile("" ::: "memory");
    if (t + 2 < nt) stage((t + 2) % 3);
    compute(t % 3);
  }

  // epilogue: C/D layout col=lane&15, row=(lane>>4)*4+reg  [m89/m91 verified]
#pragma unroll
  for (int i = 0; i < 4; ++i) {
    const int mrow = m0 + mw + i * 16 + qd * 4;
#pragma unroll
    for (int j = 0; j < 4; ++j) {
      const int ncol = n0 + nw + j * 16 + li;
      float bv = 0.f;
      if (EPI != EPI_ACC_F32) bv = bias[ncol];
#pragma unroll
      for (int r = 0; r < 4; ++r) {
        const size_t off2 = (size_t)(mrow + r) * N + ncol;
        float v = acc[i][j][r] + bv;
        if (EPI == EPI_BIAS_RES_F32) {
          ((float*)out)[off2] = v + (float)R[off2];
        } else if (EPI == EPI_BIAS_GELU) {
          ((bf16*)out)[off2] = (bf16)gelu_erf(v);
        } else if (EPI == EPI_ACC_F32) {
          ((float*)out)[off2] += v;
        } else {
          ((bf16*)out)[off2] = (bf16)v;
        }
      }
    }
  }
}

// ---------------------------------------------------------------------------
// MFMA attention: one block (4 waves) per (sequence, head).
// P padded to PP (16-mult) for tiles; K-dim of PV padded to PK (32-mult).
// ---------------------------------------------------------------------------
template <int P>
__global__ __launch_bounds__(256) void attn_kernel(const bf16* __restrict__ qkv,
                                                   bf16* __restrict__ out) {
  constexpr int PP   = ((P + 15) / 16) * 16;   // 32, 48, 96
  constexpr int PK   = ((PP + 31) / 32) * 32;  // 32, 64, 96
  constexpr int MT   = PP / 16;
  constexpr int SSTR = PP + 2;                 // fp32 words
  constexpr int VSTR = PK + 8;                 // bf16 elems; *2B is 16B-mult
  constexpr int PSTR = PK + 8;

  __shared__ __align__(16) bf16 QK[2 * PP * 64];  // Q | K ; reused as Ps
  __shared__ __align__(16) bf16 Vt[64 * VSTR];
  __shared__ __align__(16) float Sm[PP * SSTR];
  __shared__ float rsum[PP];

  bf16* Qs = QK;
  bf16* Ks = QK + PP * 64;
  bf16* Ps = QK;  // overlays Q/K after S phase (dead by then)

  const int tid  = threadIdx.x;
  const int lane = tid & 63;
  const int wv   = tid >> 6;
  const int li   = lane & 15;
  const int qd   = lane >> 4;
  const int n    = blockIdx.x >> 3;
  const int h    = blockIdx.x & 7;
  const bf16* base = qkv + (size_t)n * P * QKV_D + h * 64;

  // stage Q,K: 16B chunks, slot = c ^ (r&7)
  for (int t = tid; t < P * 8; t += 256) {
    const int r = t >> 3, c = t & 7;
    const bf16x8 qv = *(const bf16x8*)(base + (size_t)r * QKV_D + c * 8);
    const bf16x8 kv = *(const bf16x8*)(base + (size_t)r * QKV_D + 512 + c * 8);
    *(bf16x8*)(Qs + r * 64 + ((c ^ (r & 7)) * 8)) = qv;
    *(bf16x8*)(Ks + r * 64 + ((c ^ (r & 7)) * 8)) = kv;
  }
  // stage V^T
  for (int t = tid; t < P * 8; t += 256) {
    const int j = t % P, dc = t / P;
    const bf16x8 vv = *(const bf16x8*)(base + (size_t)j * QKV_D + 1024 + dc * 8);
#pragma unroll
    for (int u = 0; u < 8; ++u) Vt[(dc * 8 + u) * VSTR + j] = vv[u];
  }
  if constexpr (PK > P) {
    for (int t = tid; t < 64 * (PK - P); t += 256) {
      const int d = t / (PK - P), j = P + t % (PK - P);
      Vt[d * VSTR + j] = (bf16)0.f;
    }
  }
  __syncthreads();

  // S = Q K^T
  for (int t = wv; t < MT * MT; t += 4) {
    const int ti = t / MT, tj = t % MT;
    f32x4 acc = (f32x4){0.f, 0.f, 0.f, 0.f};
#pragma unroll
    for (int ks = 0; ks < 2; ++ks) {
      const int ck = ks * 4 + qd;
      const int ar = ti * 16 + li;
      const int br = tj * 16 + li;
      const bf16x8 af = *(const bf16x8*)(Qs + ar * 64 + ((ck ^ (ar & 7)) * 8));
      const bf16x8 bv = *(const bf16x8*)(Ks + br * 64 + ((ck ^ (br & 7)) * 8));
      acc = __builtin_amdgcn_mfma_f32_16x16x32_bf16(af, bv, acc, 0, 0, 0);
    }
#pragma unroll
    for (int r = 0; r < 4; ++r)
      Sm[(ti * 16 + qd * 4 + r) * SSTR + tj * 16 + li] = acc[r];
  }
  __syncthreads();

  // softmax row: unnormalized exp -> bf16 Ps; 1/sum saved for O-write
  if (tid < P) {
    const float* srow = Sm + tid * SSTR;
    bf16* prow = Ps + tid * PSTR;
    float mx = -1e30f;
    for (int j = 0; j < P; ++j) mx = fmaxf(mx, srow[j]);
    mx *= 0.125f;  // 1/sqrt(64)
    float sum = 0.f;
    for (int j = 0; j < P; ++j) {
      const float e = __expf(srow[j] * 0.125f - mx);
      sum += e;
      prow[j] = (bf16)e;
    }
    for (int j = P; j < PK; ++j) prow[j] = (bf16)0.f;
    rsum[tid] = 1.f / sum;
  }
  __syncthreads();

  // O = P V
  for (int t = wv; t < MT * 4; t += 4) {
    const int ti = t >> 2, td = t & 3;
    f32x4 acc = (f32x4){0.f, 0.f, 0.f, 0.f};
#pragma unroll
    for (int ks = 0; ks < PK / 32; ++ks) {
      const int ck = ks * 4 + qd;
      const bf16x8 af = *(const bf16x8*)(Ps + (ti * 16 + li) * PSTR + ck * 8);
      const bf16x8 bv = *(const bf16x8*)(Vt + (td * 16 + li) * VSTR + ck * 8);
      acc = __builtin_amdgcn_mfma_f32_16x16x32_bf16(af, bv, acc, 0, 0, 0);
    }
#pragma unroll
    for (int r = 0; r < 4; ++r) {
      const int row = ti * 16 + qd * 4 + r;
      if (row < P)
        out[(size_t)(n * P + row) * HID + h * 64 + td * 16 + li] =
            (bf16)(acc[r] * rsum[row]);
    }
  }
}

// ---------------------------------------------------------------------------
// LayerNorm over 512, one wave per row. float4 loads, bf16x4 stores.
// ---------------------------------------------------------------------------
__global__ __launch_bounds__(256) void ln_kernel(const float* __restrict__ Y,
                                                 const float* __restrict__ w,
                                                 const float* __restrict__ b,
                                                 bf16* __restrict__ X) {
  const int row  = blockIdx.x * 4 + (threadIdx.x >> 6);
  const int lane = threadIdx.x & 63;
  const float4* y4 = (const float4*)(Y + (size_t)row * HID);
  const float4 u = y4[lane];
  const float4 v = y4[lane + 64];
  float s  = u.x + u.y + u.z + u.w + v.x + v.y + v.z + v.w;
  float s2 = u.x*u.x + u.y*u.y + u.z*u.z + u.w*u.w +
             v.x*v.x + v.y*v.y + v.z*v.z + v.w*v.w;
#pragma unroll
  for (int off = 32; off > 0; off >>= 1) {
    s  += __shfl_xor(s, off, 64);
    s2 += __shfl_xor(s2, off, 64);
  }
  const float mean = s * (1.f / 512.f);
  const float var  = s2 * (1.f / 512.f) - mean * mean;
  const float rstd = rsqrtf(var + 1e-5f);
  const float4 w0 = ((const float4*)w)[lane];
  const float4 w1 = ((const float4*)w)[lane + 64];
  const float4 b0 = ((const float4*)b)[lane];
  const float4 b1 = ((const float4*)b)[lane + 64];
  bf16* xr = X + (size_t)row * HID;
  bf16x4 o0 = {(bf16)((u.x - mean) * rstd * w0.x + b0.x),
               (bf16)((u.y - mean) * rstd * w0.y + b0.y),
               (bf16)((u.z - mean) * rstd * w0.z + b0.z),
               (bf16)((u.w - mean) * rstd * w0.w + b0.w)};
  bf16x4 o1 = {(bf16)((v.x - mean) * rstd * w1.x + b1.x),
               (bf16)((v.y - mean) * rstd * w1.y + b1.y),
               (bf16)((v.z - mean) * rstd * w1.z + b1.z),
               (bf16)((v.w - mean) * rstd * w1.w + b1.w)};
  *(bf16x4*)(xr + 4 * lane)       = o0;
  *(bf16x4*)(xr + 256 + 4 * lane) = o1;
}

// ---------------------------------------------------------------------------
// input projection: h[r,o] = sum_k x[r,k]*w[o,k] + b[o], K=7. Writes the same
// value to nbr consecutive [TOKENS,HID] slices (branches share the input).
// ---------------------------------------------------------------------------
__global__ __launch_bounds__(256) void inproj_kernel(const float* __restrict__ x,
                                                     const float* __restrict__ w,
                                                     const float* __restrict__ b,
                                                     bf16* __restrict__ h,
                                                     int nbr) {
  const int idx = blockIdx.x * 256 + threadIdx.x;
  const int r = idx >> 9, o = idx & 511;
  float s = b[o];
#pragma unroll
  for (int k = 0; k < 7; ++k) s += x[r * 7 + k] * w[o * 7 + k];
  const bf16 bv = (bf16)s;
  for (int q = 0; q < nbr; ++q) h[idx + (size_t)q * TOKENS * HID] = bv;
}

// acc[row] (+)= X[row,:] . w  (per-branch final projection accumulate)
__global__ __launch_bounds__(256) void outdot_kernel(const bf16* __restrict__ X,
                                                     const float* __restrict__ w,
                                                     float* __restrict__ acc,
                                                     int first) {
  const int row  = blockIdx.x * 4 + (threadIdx.x >> 6);
  const int lane = threadIdx.x & 63;
  const bf16* xr = X + (size_t)row * HID;
  const bf16x8 xa = *(const bf16x8*)(xr + 8 * lane);
  const float4 wa = ((const float4*)w)[2 * lane];
  const float4 wb = ((const float4*)w)[2 * lane + 1];
  float s = (float)xa[0] * wa.x + (float)xa[1] * wa.y + (float)xa[2] * wa.z +
            (float)xa[3] * wa.w + (float)xa[4] * wb.x + (float)xa[5] * wb.y +
            (float)xa[6] * wb.z + (float)xa[7] * wb.w;
#pragma unroll
  for (int off = 32; off > 0; off >>= 1) s += __shfl_xor(s, off, 64);
  if (lane == 0) acc[row] = first ? s : (acc[row] + s);
}

// out[b,o] = (1/30) * sum_{j<10} acc[b*960 + o*10 + j] + b_out   (fp32 out)
__global__ __launch_bounds__(256) void pool_kernel(const float* __restrict__ acc,
                                                   const float* __restrict__ ob,
                                                   float* __restrict__ out) {
  const int idx = blockIdx.x * 256 + threadIdx.x;
  if (idx >= 16 * 96) return;
  const int bb = idx / 96, o = idx % 96;
  float s = 0.f;
#pragma unroll
  for (int j = 0; j < 10; ++j) s += acc[bb * 960 + o * 10 + j];
  out[idx] = s * (1.f / 30.f) + ob[0];
}

// ---------------------------------------------------------------------------
extern "C" void kernel_launch(void* const* d_in, const int* in_sizes, int n_in,
                              void* d_out, int out_size, void* d_ws,
                              size_t ws_size, hipStream_t stream) {
  const float* x          = (const float*)d_in[0];
  const float* ip_w       = (const float*)d_in[1];
  const float* ip_b       = (const float*)d_in[2];
  const float* in_proj_w  = (const float*)d_in[3];
  const float* in_proj_b  = (const float*)d_in[4];
  const float* out_proj_w = (const float*)d_in[5];
  const float* out_proj_b = (const float*)d_in[6];
  const float* ffn_w1     = (const float*)d_in[7];
  const float* ffn_b1     = (const float*)d_in[8];
  const float* ffn_w2     = (const float*)d_in[9];
  const float* ffn_b2     = (const float*)d_in[10];
  const float* ln1_w      = (const float*)d_in[11];
  const float* ln1_b      = (const float*)d_in[12];
  const float* ln2_w      = (const float*)d_in[13];
  const float* ln2_b      = (const float*)d_in[14];
  const float* op_w       = (const float*)d_in[15];
  const float* op_b       = (const float*)d_in[16];

  // fixed carve: weights + ACC, then activations (path-dependent)
  char* p = (char*)d_ws;
  bf16* Wq  = (bf16*)p; p += (size_t)4 * QKV_D * HID * 2;
  bf16* Wo  = (bf16*)p; p += (size_t)4 * HID * HID * 2;
  bf16* W1  = (bf16*)p; p += (size_t)4 * FFN_D * HID * 2;
  bf16* W2s = (bf16*)p; p += (size_t)4 * HID * FFN_D * 2;  // split layout
  float* ACC = (float*)p; p += (size_t)TOKENS * 4;
  const size_t remain = ws_size - (size_t)(p - (char*)d_ws);

  const size_t T3 = 3 * (size_t)TOKENS;
  // batched: X bf16 [T3,512] + BUF bf16 [T3,2048]; inside BUF, by liveness:
  //   QKV [0,1536) | ATT [1536,2048)     (attention phase)
  //   Y0 fp32 [0,1024)                   (Wo out -> LN1; QKV region dead)
  //   H bf16 [0,1024) | Y2 fp32 [1024,2048)  (FFN halves; ATT dead)
  const size_t need_batched = T3 * HID * 2 + T3 * (size_t)FFN_D * 2;  // ~236 MB
  const size_t need_seq =
      (size_t)TOKENS * HID * 4 + (size_t)TOKENS * HID * 2 +
      (size_t)TOKENS * FFN_D * 2;                                     // ~110 MB
  const bool batched = remain >= need_batched;
  if (!batched && remain < need_seq) return;

  {  // weight conversion fp32 -> bf16
    const int nq = 4 * QKV_D * HID / 4, no = 4 * HID * HID / 4,
              n1 = 4 * FFN_D * HID / 4, n2 = 4 * HID * FFN_D / 4;
    cvt_kernel<<<(nq + 255) / 256, 256, 0, stream>>>(in_proj_w, Wq, nq);
    cvt_kernel<<<(no + 255) / 256, 256, 0, stream>>>(out_proj_w, Wo, no);
    cvt_kernel<<<(n1 + 255) / 256, 256, 0, stream>>>(ffn_w1, W1, n1);
    cvt_w2_kernel<<<(n2 + 255) / 256, 256, 0, stream>>>(ffn_w2, W2s, n2);
  }

  static const int periods[3] = {24, 48, 96};
  auto launch_attn = [&](int P, const bf16* q, bf16* o) {
    const int nblk = (TOKENS / P) * 8;
    if (P == 24)      attn_kernel<24><<<nblk, 256, 0, stream>>>(q, o);
    else if (P == 48) attn_kernel<48><<<nblk, 256, 0, stream>>>(q, o);
    else              attn_kernel<96><<<nblk, 256, 0, stream>>>(q, o);
  };

  // one transformer layer on M rows; buffers per the liveness overlay above
  auto run_layer = [&](int l, int M, bf16* X, bf16* QKV, bf16* ATT,
                       float* Y0, bf16* H, float* Y2, bool all_br, int br) {
    const int MB = M / 256;
    gemm_bt<EPI_BIAS_BF16><<<dim3(MB, QKV_D / 128), 512, 0, stream>>>(
        X, Wq + (size_t)l * QKV_D * HID, in_proj_b + l * QKV_D, nullptr,
        QKV, M, QKV_D, HID);
    if (all_br) {
      for (int b2 = 0; b2 < 3; ++b2)
        launch_attn(periods[b2], QKV + (size_t)b2 * TOKENS * QKV_D,
                    ATT + (size_t)b2 * TOKENS * HID);
    } else {
      launch_attn(periods[br], QKV, ATT);
    }
    gemm_bt<EPI_BIAS_RES_F32><<<dim3(MB, HID / 128), 512, 0, stream>>>(
        ATT, Wo + (size_t)l * HID * HID, out_proj_b + l * HID, X, Y0,
        M, HID, HID);
    ln_kernel<<<M / 4, 256, 0, stream>>>(Y0, ln1_w + l * HID, ln1_b + l * HID, X);
    // FFN split into two K=1024 halves (W2 pre-split so rows are contiguous)
    gemm_bt<EPI_BIAS_GELU><<<dim3(MB, 1024 / 128), 512, 0, stream>>>(
        X, W1 + (size_t)l * FFN_D * HID, ffn_b1 + l * FFN_D, nullptr,
        H, M, 1024, HID);
    gemm_bt<EPI_BIAS_RES_F32><<<dim3(MB, HID / 128), 512, 0, stream>>>(
        H, W2s + (size_t)(l * 2 + 0) * HID * 1024, ffn_b2 + l * HID, X, Y2,
        M, HID, 1024);
    gemm_bt<EPI_BIAS_GELU><<<dim3(MB, 1024 / 128), 512, 0, stream>>>(
        X, W1 + (size_t)l * FFN_D * HID + (size_t)1024 * HID,
        ffn_b1 + l * FFN_D + 1024, nullptr, H, M, 1024, HID);
    gemm_bt<EPI_ACC_F32><<<dim3(MB, HID / 128), 512, 0, stream>>>(
        H, W2s + (size_t)(l * 2 + 1) * HID * 1024, nullptr, nullptr, Y2,
        M, HID, 1024);
    ln_kernel<<<M / 4, 256, 0, stream>>>(Y2, ln2_w + l * HID, ln2_b + l * HID, X);
  };

  if (batched) {
    bf16* X   = (bf16*)p; p += T3 * HID * 2;
    bf16* BUF = (bf16*)p;
    bf16*  QKV = BUF;
    bf16*  ATT = BUF + T3 * QKV_D;
    float* Y0  = (float*)BUF;
    bf16*  H   = BUF;
    float* Y2  = (float*)(BUF + T3 * 1024);
    const int M = (int)T3;

    inproj_kernel<<<TOKENS * HID / 256, 256, 0, stream>>>(x, ip_w, ip_b, X, 3);
    for (int l = 0; l < 4; ++l)
      run_layer(l, M, X, QKV, ATT, Y0, H, Y2, true, 0);
    for (int br = 0; br < 3; ++br)
      outdot_kernel<<<TOKENS / 4, 256, 0, stream>>>(
          X + (size_t)br * TOKENS * HID, op_w, ACC, br == 0);
  } else {
    // sequential (fits in ~135 MB)
    float* Y  = (float*)p; p += (size_t)TOKENS * HID * 4;
    bf16* X   = (bf16*)p;  p += (size_t)TOKENS * HID * 2;
    bf16* SCR = (bf16*)p;  p += (size_t)TOKENS * FFN_D * 2;
    bf16*  QKV = SCR;
    bf16*  ATT = SCR + (size_t)TOKENS * QKV_D;
    bf16*  H   = SCR;   // reuses QKV region (dead after attention)
    const int M = TOKENS;

    for (int br = 0; br < 3; ++br) {
      inproj_kernel<<<TOKENS * HID / 256, 256, 0, stream>>>(x, ip_w, ip_b, X, 1);
      for (int l = 0; l < 4; ++l)
        run_layer(l, M, X, QKV, ATT, Y, H, Y, false, br);
      outdot_kernel<<<TOKENS / 4, 256, 0, stream>>>(X, op_w, ACC, br == 0);
    }
  }
  pool_kernel<<<6, 256, 0, stream>>>(ACC, op_b, (float*)d_out);
}

// Round 3
// 2764.804 us; speedup vs baseline: 1.1007x; 1.1007x over previous
//
#include <hip/hip_runtime.h>
#include <hip/hip_bf16.h>

typedef __bf16 bf16;
typedef __attribute__((ext_vector_type(8))) __bf16 bf16x8;
typedef __attribute__((ext_vector_type(4))) __bf16 bf16x4;
typedef __attribute__((ext_vector_type(4))) float f32x4;

#define TOKENS 15360   // B*S = 16*960
#define HID    512
#define FFN_D  2048
#define QKV_D  1536

// ---------------------------------------------------------------------------
// fast exact-GELU: A&S 7.1.26 erf (|eps|<=1.5e-7), hw exp + hw rcp
// ---------------------------------------------------------------------------
__device__ __forceinline__ float gelu_erf(float x) {
  const float z = fabsf(x) * 0.70710678118654752f;
#if __has_builtin(__builtin_amdgcn_rcpf)
  const float t = __builtin_amdgcn_rcpf(fmaf(0.3275911f, z, 1.f));
#else
  const float t = 1.f / fmaf(0.3275911f, z, 1.f);
#endif
  float p = fmaf(1.061405429f, t, -1.453152027f);
  p = fmaf(p, t, 1.421413741f);
  p = fmaf(p, t, -0.284496736f);
  p = fmaf(p, t, 0.254829592f);
  p *= t;
  const float e  = __expf(-z * z);
  const float er = fmaf(-p, e, 1.f);          // erf(|x|/sqrt2)
  return 0.5f * x * (1.f + copysignf(er, x));
}

// ---------------------------------------------------------------------------
// fp32 -> bf16 weight conversion (run every launch; ws is re-poisoned)
// ---------------------------------------------------------------------------
__global__ __launch_bounds__(256) void cvt_kernel(const float* __restrict__ src,
                                                  bf16* __restrict__ dst, int n4) {
  const int i = (blockIdx.x * 256 + threadIdx.x);
  if (i >= n4) return;
  const float4 v = ((const float4*)src)[i];
  bf16x4 d = {(bf16)v.x, (bf16)v.y, (bf16)v.z, (bf16)v.w};
  *(bf16x4*)(dst + (size_t)i * 4) = d;
}

// W2 [4][512][2048] fp32 -> split bf16 [4][2][512][1024]:
// dst[l][h][n][c] = src[l][n][h*1024+c]  (so each K=1024 half has contiguous rows)
__global__ __launch_bounds__(256) void cvt_w2_kernel(const float* __restrict__ src,
                                                     bf16* __restrict__ dst, int n4) {
  const int i = (blockIdx.x * 256 + threadIdx.x);
  if (i >= n4) return;
  const int f  = i * 4;
  const int ln = f >> 11;        // l*512 + n
  const int c2 = f & 2047;
  const int h  = c2 >> 10;
  const int c  = c2 & 1023;
  const int l  = ln >> 9;
  const int n  = ln & 511;
  const float4 v = ((const float4*)src)[i];
  bf16x4 d = {(bf16)v.x, (bf16)v.y, (bf16)v.z, (bf16)v.w};
  *(bf16x4*)(dst + ((((size_t)(l * 2 + h) * 512 + n) << 10) + c)) = d;
}

// ---------------------------------------------------------------------------
// GEMM: C[M,N] = A[M,K] @ W[N,K]^T (+bias fp32, + optional residual / GELU /
// fp32-accumulate).
// 256x256 tile, BK=64, 512 threads = 8 waves (2M x 4N), per-wave 128x64 via
// 8x4 mfma_f32_16x16x32_bf16. Double-buffered LDS (128 KB). 8-phase-style
// schedule: per K-tile, 4 fine phases, each {ds_read subtile -> barrier ->
// setprio(1) 16 MFMA setprio(0) -> barrier}. Whole next K-tile staged at
// iteration top BEFORE a counted s_waitcnt vmcnt(8) gate (8 = next tile's
// loads in flight; in-order retirement => current tile landed). vmcnt never
// drains to 0 except the last K-tile.
// Sync audit: stage(t+1 -> buf b^1) is issued only after iteration t-1's
// final phase barrier, which each wave reaches only after its MFMAs consumed
// all reads of buf b^1 -- no alias. The barrier after the per-wave vmcnt
// gate covers cross-wave staging (vmcnt is per-wave).
// Grid = (N/256, M/256); XCD-chunked logical id walks n fastest within an
// m-panel per XCD -> A-panel + B stay L2-resident (fetch ~= A once + B once).
// XOR swizzle (slot s holds k-chunk s^(r&7)) keeps global_load_lds linear-dest
// contiguity AND makes ds_read_b128 conflict-free (measured 0).
// ---------------------------------------------------------------------------
#define EPI_BIAS_BF16     0
#define EPI_BIAS_RES_F32  1
#define EPI_BIAS_GELU     2
#define EPI_ACC_F32       3   // out(fp32) += acc  (no bias, no residual)

template <int EPI>
__global__ __launch_bounds__(512, 2) void gemm_bt(
    const bf16* __restrict__ A, const bf16* __restrict__ W,
    const float* __restrict__ bias, const bf16* __restrict__ R,
    void* __restrict__ out, int M, int N, int K) {
  __shared__ __align__(16) bf16 As[2 * 256 * 64];   // 64 KB
  __shared__ __align__(16) bf16 Bs[2 * 256 * 64];   // 64 KB

  const int tid  = threadIdx.x;
  const int lane = tid & 63;
  const int wv   = tid >> 6;
  const int li   = lane & 15;
  const int qd   = lane >> 4;
  const int wm   = wv >> 2;          // 2 m-waves of 128 rows
  const int wn   = wv & 3;           // 4 n-waves of 64 cols

  // XCD-chunked, n-fastest logical ordering (nwg % 8 == 0 for all shapes)
  const int gx  = gridDim.x;                  // N / 256
  const int nwg = gx * gridDim.y;
  int lid = blockIdx.y * gx + blockIdx.x;
  if ((nwg & 7) == 0) lid = (lid & 7) * (nwg >> 3) + (lid >> 3);
  const int n0 = (lid % gx) << 8;
  const int m0 = (lid / gx) << 8;

  f32x4 acc[8][4];
#pragma unroll
  for (int i = 0; i < 8; ++i)
#pragma unroll
    for (int j = 0; j < 4; ++j) acc[i][j] = (f32x4){0.f, 0.f, 0.f, 0.f};

  // staging: A tile 256x64 = 2048 16B-chunks (4 loads/thread), B same.
  // chunk q -> row r=q>>3, slot s=q&7; source k-chunk = s^(r&7)
  // (pre-swizzled source, linear LDS dest).
  const bf16* pa[4];
  const bf16* pb[4];
  int oa[4];
#pragma unroll
  for (int l = 0; l < 4; ++l) {
    const int q = l * 512 + tid;
    const int r = q >> 3, s = q & 7;
    pa[l] = A + (size_t)(m0 + r) * K + ((s ^ (r & 7)) << 3);
    pb[l] = W + (size_t)(n0 + r) * K + ((s ^ (r & 7)) << 3);
    oa[l] = (l * 512 + (tid & 448)) << 3;   // wave-uniform LDS base (elems)
  }

  auto stage = [&](int buf) {   // 8 global_load_lds per thread (4 A + 4 B)
#pragma unroll
    for (int l = 0; l < 4; ++l) {
      __builtin_amdgcn_global_load_lds(
          (const __attribute__((address_space(1))) unsigned int*)pa[l],
          (__attribute__((address_space(3))) unsigned int*)(As + buf * 16384 + oa[l]),
          16, 0, 0);
      pa[l] += 64;
    }
#pragma unroll
    for (int l = 0; l < 4; ++l) {
      __builtin_amdgcn_global_load_lds(
          (const __attribute__((address_space(1))) unsigned int*)pb[l],
          (__attribute__((address_space(3))) unsigned int*)(Bs + buf * 16384 + oa[l]),
          16, 0, 0);
      pb[l] += 64;
    }
  };

  bf16x8 Afr[4][2], Bfr[2][2];

  auto loadA = [&](const bf16* Ab, int half) {   // 8 x ds_read_b128
#pragma unroll
    for (int i = 0; i < 4; ++i) {
      const int mr = wm * 128 + half * 64 + i * 16 + li;   // mr&7 == li&7
#pragma unroll
      for (int ks = 0; ks < 2; ++ks) {
        const int ck = ks * 4 + qd;
        Afr[i][ks] = *(const bf16x8*)(Ab + mr * 64 + ((ck ^ (li & 7)) << 3));
      }
    }
  };
  auto loadB = [&](const bf16* Bb, int half) {   // 4 x ds_read_b128
#pragma unroll
    for (int j = 0; j < 2; ++j) {
      const int nr = wn * 64 + half * 32 + j * 16 + li;    // nr&7 == li&7
#pragma unroll
      for (int ks = 0; ks < 2; ++ks) {
        const int ck = ks * 4 + qd;
        Bfr[j][ks] = *(const bf16x8*)(Bb + nr * 64 + ((ck ^ (li & 7)) << 3));
      }
    }
  };

  auto phase = [&](int ih, int jh) {   // barrier -> 16 MFMA -> barrier
    asm volatile("" ::: "memory");
    __builtin_amdgcn_s_barrier();
    __builtin_amdgcn_s_setprio(1);
#pragma unroll
    for (int ks = 0; ks < 2; ++ks)
#pragma unroll
      for (int i = 0; i < 4; ++i)
#pragma unroll
        for (int j = 0; j < 2; ++j)
          acc[ih * 4 + i][jh * 2 + j] = __builtin_amdgcn_mfma_f32_16x16x32_bf16(
              Afr[i][ks], Bfr[j][ks], acc[ih * 4 + i][jh * 2 + j], 0, 0, 0);
    __builtin_amdgcn_s_setprio(0);
    asm volatile("" ::: "memory");
    __builtin_amdgcn_s_barrier();
    asm volatile("" ::: "memory");
  };

  const int nt = K >> 6;   // 8 (K=512) or 16 (K=1024)
  stage(0);
  for (int t = 0; t < nt; ++t) {
    const int b = t & 1;
    if (t + 1 < nt) {
      stage(b ^ 1);
      asm volatile("s_waitcnt vmcnt(8)" ::: "memory");  // tile t landed
    } else {
      asm volatile("s_waitcnt vmcnt(0)" ::: "memory");
    }
    __builtin_amdgcn_s_barrier();   // all waves' tile-t loads landed
    asm volatile("" ::: "memory");

    const bf16* Ab = As + b * 16384;
    const bf16* Bb = Bs + b * 16384;
    // 4 fine phases: quadrant MFMA bursts with per-phase barriers
    loadA(Ab, 0); loadB(Bb, 0);  phase(0, 0);
    loadB(Bb, 1);                phase(0, 1);
    loadA(Ab, 1);                phase(1, 1);
    loadB(Bb, 0);                phase(1, 0);
  }

  // epilogue: C/D layout col=lane&15, row=(lane>>4)*4+reg  [m89/m91 verified]
#pragma unroll
  for (int i = 0; i < 8; ++i) {
    const int mrow = m0 + wm * 128 + i * 16 + qd * 4;
#pragma unroll
    for (int j = 0; j < 4; ++j) {
      const int ncol = n0 + wn * 64 + j * 16 + li;
      float bv = 0.f;
      if (EPI != EPI_ACC_F32) bv = bias[ncol];
#pragma unroll
      for (int r = 0; r < 4; ++r) {
        const size_t off2 = (size_t)(mrow + r) * N + ncol;
        float v = acc[i][j][r] + bv;
        if (EPI == EPI_BIAS_RES_F32) {
          ((float*)out)[off2] = v + (float)R[off2];
        } else if (EPI == EPI_BIAS_GELU) {
          ((bf16*)out)[off2] = (bf16)gelu_erf(v);
        } else if (EPI == EPI_ACC_F32) {
          ((float*)out)[off2] += v;
        } else {
          ((bf16*)out)[off2] = (bf16)v;
        }
      }
    }
  }
}

// ---------------------------------------------------------------------------
// MFMA attention: one block (4 waves) per (sequence, head).
// P padded to PP (16-mult) for tiles; K-dim of PV padded to PK (32-mult).
// ---------------------------------------------------------------------------
template <int P>
__global__ __launch_bounds__(256) void attn_kernel(const bf16* __restrict__ qkv,
                                                   bf16* __restrict__ out) {
  constexpr int PP   = ((P + 15) / 16) * 16;   // 32, 48, 96
  constexpr int PK   = ((PP + 31) / 32) * 32;  // 32, 64, 96
  constexpr int MT   = PP / 16;
  constexpr int SSTR = PP + 2;                 // fp32 words
  constexpr int VSTR = PK + 8;                 // bf16 elems; *2B is 16B-mult
  constexpr int PSTR = PK + 8;

  __shared__ __align__(16) bf16 QK[2 * PP * 64];  // Q | K ; reused as Ps
  __shared__ __align__(16) bf16 Vt[64 * VSTR];
  __shared__ __align__(16) float Sm[PP * SSTR];
  __shared__ float rsum[PP];

  bf16* Qs = QK;
  bf16* Ks = QK + PP * 64;
  bf16* Ps = QK;  // overlays Q/K after S phase (dead by then)

  const int tid  = threadIdx.x;
  const int lane = tid & 63;
  const int wv   = tid >> 6;
  const int li   = lane & 15;
  const int qd   = lane >> 4;
  const int n    = blockIdx.x >> 3;
  const int h    = blockIdx.x & 7;
  const bf16* base = qkv + (size_t)n * P * QKV_D + h * 64;

  // stage Q,K: 16B chunks, slot = c ^ (r&7)
  for (int t = tid; t < P * 8; t += 256) {
    const int r = t >> 3, c = t & 7;
    const bf16x8 qv = *(const bf16x8*)(base + (size_t)r * QKV_D + c * 8);
    const bf16x8 kv = *(const bf16x8*)(base + (size_t)r * QKV_D + 512 + c * 8);
    *(bf16x8*)(Qs + r * 64 + ((c ^ (r & 7)) * 8)) = qv;
    *(bf16x8*)(Ks + r * 64 + ((c ^ (r & 7)) * 8)) = kv;
  }
  // stage V^T
  for (int t = tid; t < P * 8; t += 256) {
    const int j = t % P, dc = t / P;
    const bf16x8 vv = *(const bf16x8*)(base + (size_t)j * QKV_D + 1024 + dc * 8);
#pragma unroll
    for (int u = 0; u < 8; ++u) Vt[(dc * 8 + u) * VSTR + j] = vv[u];
  }
  if constexpr (PK > P) {
    for (int t = tid; t < 64 * (PK - P); t += 256) {
      const int d = t / (PK - P), j = P + t % (PK - P);
      Vt[d * VSTR + j] = (bf16)0.f;
    }
  }
  __syncthreads();

  // S = Q K^T
  for (int t = wv; t < MT * MT; t += 4) {
    const int ti = t / MT, tj = t % MT;
    f32x4 acc = (f32x4){0.f, 0.f, 0.f, 0.f};
#pragma unroll
    for (int ks = 0; ks < 2; ++ks) {
      const int ck = ks * 4 + qd;
      const int ar = ti * 16 + li;
      const int br = tj * 16 + li;
      const bf16x8 af = *(const bf16x8*)(Qs + ar * 64 + ((ck ^ (ar & 7)) * 8));
      const bf16x8 bv = *(const bf16x8*)(Ks + br * 64 + ((ck ^ (br & 7)) * 8));
      acc = __builtin_amdgcn_mfma_f32_16x16x32_bf16(af, bv, acc, 0, 0, 0);
    }
#pragma unroll
    for (int r = 0; r < 4; ++r)
      Sm[(ti * 16 + qd * 4 + r) * SSTR + tj * 16 + li] = acc[r];
  }
  __syncthreads();

  // softmax row: unnormalized exp -> bf16 Ps; 1/sum saved for O-write
  if (tid < P) {
    const float* srow = Sm + tid * SSTR;
    bf16* prow = Ps + tid * PSTR;
    float mx = -1e30f;
    for (int j = 0; j < P; ++j) mx = fmaxf(mx, srow[j]);
    mx *= 0.125f;  // 1/sqrt(64)
    float sum = 0.f;
    for (int j = 0; j < P; ++j) {
      const float e = __expf(srow[j] * 0.125f - mx);
      sum += e;
      prow[j] = (bf16)e;
    }
    for (int j = P; j < PK; ++j) prow[j] = (bf16)0.f;
    rsum[tid] = 1.f / sum;
  }
  __syncthreads();

  // O = P V
  for (int t = wv; t < MT * 4; t += 4) {
    const int ti = t >> 2, td = t & 3;
    f32x4 acc = (f32x4){0.f, 0.f, 0.f, 0.f};
#pragma unroll
    for (int ks = 0; ks < PK / 32; ++ks) {
      const int ck = ks * 4 + qd;
      const bf16x8 af = *(const bf16x8*)(Ps + (ti * 16 + li) * PSTR + ck * 8);
      const bf16x8 bv = *(const bf16x8*)(Vt + (td * 16 + li) * VSTR + ck * 8);
      acc = __builtin_amdgcn_mfma_f32_16x16x32_bf16(af, bv, acc, 0, 0, 0);
    }
#pragma unroll
    for (int r = 0; r < 4; ++r) {
      const int row = ti * 16 + qd * 4 + r;
      if (row < P)
        out[(size_t)(n * P + row) * HID + h * 64 + td * 16 + li] =
            (bf16)(acc[r] * rsum[row]);
    }
  }
}

// ---------------------------------------------------------------------------
// LayerNorm over 512, one wave per row. float4 loads, bf16x4 stores.
// ---------------------------------------------------------------------------
__global__ __launch_bounds__(256) void ln_kernel(const float* __restrict__ Y,
                                                 const float* __restrict__ w,
                                                 const float* __restrict__ b,
                                                 bf16* __restrict__ X) {
  const int row  = blockIdx.x * 4 + (threadIdx.x >> 6);
  const int lane = threadIdx.x & 63;
  const float4* y4 = (const float4*)(Y + (size_t)row * HID);
  const float4 u = y4[lane];
  const float4 v = y4[lane + 64];
  float s  = u.x + u.y + u.z + u.w + v.x + v.y + v.z + v.w;
  float s2 = u.x*u.x + u.y*u.y + u.z*u.z + u.w*u.w +
             v.x*v.x + v.y*v.y + v.z*v.z + v.w*v.w;
#pragma unroll
  for (int off = 32; off > 0; off >>= 1) {
    s  += __shfl_xor(s, off, 64);
    s2 += __shfl_xor(s2, off, 64);
  }
  const float mean = s * (1.f / 512.f);
  const float var  = s2 * (1.f / 512.f) - mean * mean;
  const float rstd = rsqrtf(var + 1e-5f);
  const float4 w0 = ((const float4*)w)[lane];
  const float4 w1 = ((const float4*)w)[lane + 64];
  const float4 b0 = ((const float4*)b)[lane];
  const float4 b1 = ((const float4*)b)[lane + 64];
  bf16* xr = X + (size_t)row * HID;
  bf16x4 o0 = {(bf16)((u.x - mean) * rstd * w0.x + b0.x),
               (bf16)((u.y - mean) * rstd * w0.y + b0.y),
               (bf16)((u.z - mean) * rstd * w0.z + b0.z),
               (bf16)((u.w - mean) * rstd * w0.w + b0.w)};
  bf16x4 o1 = {(bf16)((v.x - mean) * rstd * w1.x + b1.x),
               (bf16)((v.y - mean) * rstd * w1.y + b1.y),
               (bf16)((v.z - mean) * rstd * w1.z + b1.z),
               (bf16)((v.w - mean) * rstd * w1.w + b1.w)};
  *(bf16x4*)(xr + 4 * lane)       = o0;
  *(bf16x4*)(xr + 256 + 4 * lane) = o1;
}

// ---------------------------------------------------------------------------
// input projection: h[r,o] = sum_k x[r,k]*w[o,k] + b[o], K=7. Writes the same
// value to nbr consecutive [TOKENS,HID] slices (branches share the input).
// ---------------------------------------------------------------------------
__global__ __launch_bounds__(256) void inproj_kernel(const float* __restrict__ x,
                                                     const float* __restrict__ w,
                                                     const float* __restrict__ b,
                                                     bf16* __restrict__ h,
                                                     int nbr) {
  const int idx = blockIdx.x * 256 + threadIdx.x;
  const int r = idx >> 9, o = idx & 511;
  float s = b[o];
#pragma unroll
  for (int k = 0; k < 7; ++k) s += x[r * 7 + k] * w[o * 7 + k];
  const bf16 bv = (bf16)s;
  for (int q = 0; q < nbr; ++q) h[idx + (size_t)q * TOKENS * HID] = bv;
}

// acc[row] (+)= X[row,:] . w  (per-branch final projection accumulate)
__global__ __launch_bounds__(256) void outdot_kernel(const bf16* __restrict__ X,
                                                     const float* __restrict__ w,
                                                     float* __restrict__ acc,
                                                     int first) {
  const int row  = blockIdx.x * 4 + (threadIdx.x >> 6);
  const int lane = threadIdx.x & 63;
  const bf16* xr = X + (size_t)row * HID;
  const bf16x8 xa = *(const bf16x8*)(xr + 8 * lane);
  const float4 wa = ((const float4*)w)[2 * lane];
  const float4 wb = ((const float4*)w)[2 * lane + 1];
  float s = (float)xa[0] * wa.x + (float)xa[1] * wa.y + (float)xa[2] * wa.z +
            (float)xa[3] * wa.w + (float)xa[4] * wb.x + (float)xa[5] * wb.y +
            (float)xa[6] * wb.z + (float)xa[7] * wb.w;
#pragma unroll
  for (int off = 32; off > 0; off >>= 1) s += __shfl_xor(s, off, 64);
  if (lane == 0) acc[row] = first ? s : (acc[row] + s);
}

// out[b,o] = (1/30) * sum_{j<10} acc[b*960 + o*10 + j] + b_out   (fp32 out)
__global__ __launch_bounds__(256) void pool_kernel(const float* __restrict__ acc,
                                                   const float* __restrict__ ob,
                                                   float* __restrict__ out) {
  const int idx = blockIdx.x * 256 + threadIdx.x;
  if (idx >= 16 * 96) return;
  const int bb = idx / 96, o = idx % 96;
  float s = 0.f;
#pragma unroll
  for (int j = 0; j < 10; ++j) s += acc[bb * 960 + o * 10 + j];
  out[idx] = s * (1.f / 30.f) + ob[0];
}

// ---------------------------------------------------------------------------
extern "C" void kernel_launch(void* const* d_in, const int* in_sizes, int n_in,
                              void* d_out, int out_size, void* d_ws,
                              size_t ws_size, hipStream_t stream) {
  const float* x          = (const float*)d_in[0];
  const float* ip_w       = (const float*)d_in[1];
  const float* ip_b       = (const float*)d_in[2];
  const float* in_proj_w  = (const float*)d_in[3];
  const float* in_proj_b  = (const float*)d_in[4];
  const float* out_proj_w = (const float*)d_in[5];
  const float* out_proj_b = (const float*)d_in[6];
  const float* ffn_w1     = (const float*)d_in[7];
  const float* ffn_b1     = (const float*)d_in[8];
  const float* ffn_w2     = (const float*)d_in[9];
  const float* ffn_b2     = (const float*)d_in[10];
  const float* ln1_w      = (const float*)d_in[11];
  const float* ln1_b      = (const float*)d_in[12];
  const float* ln2_w      = (const float*)d_in[13];
  const float* ln2_b      = (const float*)d_in[14];
  const float* op_w       = (const float*)d_in[15];
  const float* op_b       = (const float*)d_in[16];

  // fixed carve: weights + ACC, then activations (path-dependent)
  char* p = (char*)d_ws;
  bf16* Wq  = (bf16*)p; p += (size_t)4 * QKV_D * HID * 2;
  bf16* Wo  = (bf16*)p; p += (size_t)4 * HID * HID * 2;
  bf16* W1  = (bf16*)p; p += (size_t)4 * FFN_D * HID * 2;
  bf16* W2s = (bf16*)p; p += (size_t)4 * HID * FFN_D * 2;  // split layout
  float* ACC = (float*)p; p += (size_t)TOKENS * 4;
  const size_t remain = ws_size - (size_t)(p - (char*)d_ws);

  const size_t T3 = 3 * (size_t)TOKENS;
  // batched: X bf16 [T3,512] + BUF bf16 [T3,2048]; inside BUF, by liveness:
  //   QKV [0,1536) | ATT [1536,2048)     (attention phase)
  //   Y0 fp32 [0,1024)                   (Wo out -> LN1; QKV region dead)
  //   H bf16 [0,1024) | Y2 fp32 [1024,2048)  (FFN halves; ATT dead)
  const size_t need_batched = T3 * HID * 2 + T3 * (size_t)FFN_D * 2;  // ~236 MB
  const size_t need_seq =
      (size_t)TOKENS * HID * 4 + (size_t)TOKENS * HID * 2 +
      (size_t)TOKENS * FFN_D * 2;                                     // ~110 MB
  const bool batched = remain >= need_batched;
  if (!batched && remain < need_seq) return;

  {  // weight conversion fp32 -> bf16
    const int nq = 4 * QKV_D * HID / 4, no = 4 * HID * HID / 4,
              n1 = 4 * FFN_D * HID / 4, n2 = 4 * HID * FFN_D / 4;
    cvt_kernel<<<(nq + 255) / 256, 256, 0, stream>>>(in_proj_w, Wq, nq);
    cvt_kernel<<<(no + 255) / 256, 256, 0, stream>>>(out_proj_w, Wo, no);
    cvt_kernel<<<(n1 + 255) / 256, 256, 0, stream>>>(ffn_w1, W1, n1);
    cvt_w2_kernel<<<(n2 + 255) / 256, 256, 0, stream>>>(ffn_w2, W2s, n2);
  }

  static const int periods[3] = {24, 48, 96};
  auto launch_attn = [&](int P, const bf16* q, bf16* o) {
    const int nblk = (TOKENS / P) * 8;
    if (P == 24)      attn_kernel<24><<<nblk, 256, 0, stream>>>(q, o);
    else if (P == 48) attn_kernel<48><<<nblk, 256, 0, stream>>>(q, o);
    else              attn_kernel<96><<<nblk, 256, 0, stream>>>(q, o);
  };

  // one transformer layer on M rows; buffers per the liveness overlay above
  auto run_layer = [&](int l, int M, bf16* X, bf16* QKV, bf16* ATT,
                       float* Y0, bf16* H, float* Y2, bool all_br, int br) {
    const int MB = M / 256;   // grid = (N/256, M/256), n-fastest in-kernel
    gemm_bt<EPI_BIAS_BF16><<<dim3(QKV_D / 256, MB), 512, 0, stream>>>(
        X, Wq + (size_t)l * QKV_D * HID, in_proj_b + l * QKV_D, nullptr,
        QKV, M, QKV_D, HID);
    if (all_br) {
      for (int b2 = 0; b2 < 3; ++b2)
        launch_attn(periods[b2], QKV + (size_t)b2 * TOKENS * QKV_D,
                    ATT + (size_t)b2 * TOKENS * HID);
    } else {
      launch_attn(periods[br], QKV, ATT);
    }
    gemm_bt<EPI_BIAS_RES_F32><<<dim3(HID / 256, MB), 512, 0, stream>>>(
        ATT, Wo + (size_t)l * HID * HID, out_proj_b + l * HID, X, Y0,
        M, HID, HID);
    ln_kernel<<<M / 4, 256, 0, stream>>>(Y0, ln1_w + l * HID, ln1_b + l * HID, X);
    // FFN split into two K=1024 halves (W2 pre-split so rows are contiguous)
    gemm_bt<EPI_BIAS_GELU><<<dim3(1024 / 256, MB), 512, 0, stream>>>(
        X, W1 + (size_t)l * FFN_D * HID, ffn_b1 + l * FFN_D, nullptr,
        H, M, 1024, HID);
    gemm_bt<EPI_BIAS_RES_F32><<<dim3(HID / 256, MB), 512, 0, stream>>>(
        H, W2s + (size_t)(l * 2 + 0) * HID * 1024, ffn_b2 + l * HID, X, Y2,
        M, HID, 1024);
    gemm_bt<EPI_BIAS_GELU><<<dim3(1024 / 256, MB), 512, 0, stream>>>(
        X, W1 + (size_t)l * FFN_D * HID + (size_t)1024 * HID,
        ffn_b1 + l * FFN_D + 1024, nullptr, H, M, 1024, HID);
    gemm_bt<EPI_ACC_F32><<<dim3(HID / 256, MB), 512, 0, stream>>>(
        H, W2s + (size_t)(l * 2 + 1) * HID * 1024, nullptr, nullptr, Y2,
        M, HID, 1024);
    ln_kernel<<<M / 4, 256, 0, stream>>>(Y2, ln2_w + l * HID, ln2_b + l * HID, X);
  };

  if (batched) {
    bf16* X   = (bf16*)p; p += T3 * HID * 2;
    bf16* BUF = (bf16*)p;
    bf16*  QKV = BUF;
    bf16*  ATT = BUF + T3 * QKV_D;
    float* Y0  = (float*)BUF;
    bf16*  H   = BUF;
    float* Y2  = (float*)(BUF + T3 * 1024);
    const int M = (int)T3;

    inproj_kernel<<<TOKENS * HID / 256, 256, 0, stream>>>(x, ip_w, ip_b, X, 3);
    for (int l = 0; l < 4; ++l)
      run_layer(l, M, X, QKV, ATT, Y0, H, Y2, true, 0);
    for (int br = 0; br < 3; ++br)
      outdot_kernel<<<TOKENS / 4, 256, 0, stream>>>(
          X + (size_t)br * TOKENS * HID, op_w, ACC, br == 0);
  } else {
    // sequential (fits in ~135 MB)
    float* Y  = (float*)p; p += (size_t)TOKENS * HID * 4;
    bf16* X   = (bf16*)p;  p += (size_t)TOKENS * HID * 2;
    bf16* SCR = (bf16*)p;  p += (size_t)TOKENS * FFN_D * 2;
    bf16*  QKV = SCR;
    bf16*  ATT = SCR + (size_t)TOKENS * QKV_D;
    bf16*  H   = SCR;   // reuses QKV region (dead after attention)
    const int M = TOKENS;

    for (int br = 0; br < 3; ++br) {
      inproj_kernel<<<TOKENS * HID / 256, 256, 0, stream>>>(x, ip_w, ip_b, X, 1);
      for (int l = 0; l < 4; ++l)
        run_layer(l, M, X, QKV, ATT, Y, H, Y, false, br);
      outdot_kernel<<<TOKENS / 4, 256, 0, stream>>>(X, op_w, ACC, br == 0);
    }
  }
  pool_kernel<<<6, 256, 0, stream>>>(ACC, op_b, (float*)d_out);
}

// Round 5
// 2392.988 us; speedup vs baseline: 1.2717x; 1.1554x over previous
//
#include <hip/hip_runtime.h>
#include <hip/hip_bf16.h>

typedef __bf16 bf16;
typedef __attribute__((ext_vector_type(8))) __bf16 bf16x8;
typedef __attribute__((ext_vector_type(4))) __bf16 bf16x4;
typedef __attribute__((ext_vector_type(4))) float f32x4;

#define TOKENS 15360   // B*S = 16*960
#define HID    512
#define FFN_D  2048
#define QKV_D  1536

// ---------------------------------------------------------------------------
// fast exact-GELU: A&S 7.1.26 erf (|eps|<=1.5e-7), hw exp + hw rcp
// ---------------------------------------------------------------------------
__device__ __forceinline__ float gelu_erf(float x) {
  const float z = fabsf(x) * 0.70710678118654752f;
#if __has_builtin(__builtin_amdgcn_rcpf)
  const float t = __builtin_amdgcn_rcpf(fmaf(0.3275911f, z, 1.f));
#else
  const float t = 1.f / fmaf(0.3275911f, z, 1.f);
#endif
  float p = fmaf(1.061405429f, t, -1.453152027f);
  p = fmaf(p, t, 1.421413741f);
  p = fmaf(p, t, -0.284496736f);
  p = fmaf(p, t, 0.254829592f);
  p *= t;
  const float e  = __expf(-z * z);
  const float er = fmaf(-p, e, 1.f);          // erf(|x|/sqrt2)
  return 0.5f * x * (1.f + copysignf(er, x));
}

// ---------------------------------------------------------------------------
// fp32 -> bf16 weight conversion (run every launch; ws is re-poisoned)
// ---------------------------------------------------------------------------
__global__ __launch_bounds__(256) void cvt_kernel(const float* __restrict__ src,
                                                  bf16* __restrict__ dst, int n4) {
  const int i = (blockIdx.x * 256 + threadIdx.x);
  if (i >= n4) return;
  const float4 v = ((const float4*)src)[i];
  bf16x4 d = {(bf16)v.x, (bf16)v.y, (bf16)v.z, (bf16)v.w};
  *(bf16x4*)(dst + (size_t)i * 4) = d;
}

// W2 [4][512][2048] fp32 -> split bf16 [4][2][512][1024]:
// dst[l][h][n][c] = src[l][n][h*1024+c]  (so each K=1024 half has contiguous rows)
__global__ __launch_bounds__(256) void cvt_w2_kernel(const float* __restrict__ src,
                                                     bf16* __restrict__ dst, int n4) {
  const int i = (blockIdx.x * 256 + threadIdx.x);
  if (i >= n4) return;
  const int f  = i * 4;
  const int ln = f >> 11;        // l*512 + n
  const int c2 = f & 2047;
  const int h  = c2 >> 10;
  const int c  = c2 & 1023;
  const int l  = ln >> 9;
  const int n  = ln & 511;
  const float4 v = ((const float4*)src)[i];
  bf16x4 d = {(bf16)v.x, (bf16)v.y, (bf16)v.z, (bf16)v.w};
  *(bf16x4*)(dst + ((((size_t)(l * 2 + h) * 512 + n) << 10) + c)) = d;
}

// ---------------------------------------------------------------------------
// GEMM: C[M,N] = A[M,K] @ W[N,K]^T (+bias fp32, + optional residual / GELU /
// fp32-accumulate). 128x128 tile, BK=64, 4 waves, each 64x64 via 4x4
// mfma_f32_16x16x32_bf16. Double-buffered LDS, 2-phase pipeline (round-1
// schedule, best measured):
//   prologue STAGE(buf0);
//   loop { STAGE(buf^1); s_waitcnt vmcnt(8); s_barrier; compute(buf); s_barrier }
// Counted vmcnt(8) = next tile's 8 loads stay in flight; in-order VMEM
// retirement => current tile landed. Only the last K-tile drains vmcnt(0).
// Round 4/5: grid = (N/128, M/128) with XCD-chunked, n-fastest logical
// ordering -- consecutive blocks in an XCD chunk share the A m-panel
// (128xK = 128-256 KB, L2-resident) and B (<=2 MB) goes L2-resident after the
// first m-panel, so steady-state stage loads are ~200cy L2 hits instead of
// ~900cy HBM misses; the 2-phase compute window then hides them fully.
// XOR swizzle (slot c holds k-chunk c^(r&7)) keeps async-copy contiguity AND
// makes ds_read_b128 2-way (free, measured 0 conflicts).
// ---------------------------------------------------------------------------
#define EPI_BIAS_BF16     0
#define EPI_BIAS_RES_F32  1
#define EPI_BIAS_GELU     2
#define EPI_ACC_F32       3   // out(fp32) += acc  (no bias, no residual)

template <int EPI>
__global__ __launch_bounds__(256) void gemm_bt(
    const bf16* __restrict__ A, const bf16* __restrict__ W,
    const float* __restrict__ bias, const bf16* __restrict__ R,
    void* __restrict__ out, int M, int N, int K) {
  __shared__ __align__(16) bf16 As[2 * 128 * 64];
  __shared__ __align__(16) bf16 Bs[2 * 128 * 64];

  const int tid  = threadIdx.x;
  const int lane = tid & 63;
  const int wv   = tid >> 6;
  const int li   = lane & 15;
  const int qd   = lane >> 4;
  const int mw   = (wv & 1) << 6;
  const int nw   = (wv >> 1) << 6;

  // XCD-chunked, n-fastest logical ordering. grid = (NB = N/128, MB = M/128).
  // orig lid walks n fastest; chunk remap gives each XCD a contiguous lid
  // range (hardware round-robins blockIdx across 8 XCDs). nwg % 8 == 0 for
  // every shape we launch; identity fallback otherwise.
  const int NB  = gridDim.x;
  const int nwg = NB * gridDim.y;
  int lid = blockIdx.y * NB + blockIdx.x;
  if ((nwg & 7) == 0) lid = (lid & 7) * (nwg >> 3) + (lid >> 3);
  const int n0 = (lid % NB) << 7;
  const int m0 = (lid / NB) << 7;

  f32x4 acc[4][4];
#pragma unroll
  for (int i = 0; i < 4; ++i)
#pragma unroll
    for (int j = 0; j < 4; ++j) acc[i][j] = (f32x4){0.f, 0.f, 0.f, 0.f};

  // staging addresses: tid-invariant parts hoisted; pointers advance by BK
  const bf16* pa[4];
  const bf16* pb[4];
  int off[4];
#pragma unroll
  for (int it = 0; it < 4; ++it) {
    const int fc   = it * 256 + tid;
    const int r    = fc >> 3;
    const int c    = fc & 7;
    const int koff = (c ^ (r & 7)) << 3;
    pa[it]  = A + (size_t)(m0 + r) * K + koff;
    pb[it]  = W + (size_t)(n0 + r) * K + koff;
    off[it] = (it * 256 + (tid & 192)) * 8;  // wave-uniform LDS base (elems)
  }

  auto stage = [&](int buf) {   // 8 global_load_lds per thread (4 A + 4 B)
#pragma unroll
    for (int it = 0; it < 4; ++it) {
      __builtin_amdgcn_global_load_lds(
          (const __attribute__((address_space(1))) unsigned int*)pa[it],
          (__attribute__((address_space(3))) unsigned int*)(As + buf * 8192 + off[it]),
          16, 0, 0);
      pa[it] += 64;
    }
#pragma unroll
    for (int it = 0; it < 4; ++it) {
      __builtin_amdgcn_global_load_lds(
          (const __attribute__((address_space(1))) unsigned int*)pb[it],
          (__attribute__((address_space(3))) unsigned int*)(Bs + buf * 8192 + off[it]),
          16, 0, 0);
      pb[it] += 64;
    }
  };

  auto compute = [&](int buf) {
    const bf16* Ab = As + buf * 8192;
    const bf16* Bb = Bs + buf * 8192;
#pragma unroll
    for (int ks = 0; ks < 2; ++ks) {
      const int ck = (ks << 2) + qd;         // A/B frag: k-chunk = quad (+4*ks)
      bf16x8 af[4], bfv[4];
#pragma unroll
      for (int i = 0; i < 4; ++i) {
        const int mr = mw + i * 16 + li;     // mr&7 == li&7
        af[i] = *(const bf16x8*)(Ab + mr * 64 + ((ck ^ (li & 7)) << 3));
      }
#pragma unroll
      for (int j = 0; j < 4; ++j) {
        const int nr = nw + j * 16 + li;
        bfv[j] = *(const bf16x8*)(Bb + nr * 64 + ((ck ^ (li & 7)) << 3));
      }
#pragma unroll
      for (int i = 0; i < 4; ++i)
#pragma unroll
        for (int j = 0; j < 4; ++j)
          acc[i][j] = __builtin_amdgcn_mfma_f32_16x16x32_bf16(af[i], bfv[j],
                                                              acc[i][j], 0, 0, 0);
    }
  };

  stage(0);
  int cur = 0;
  for (int k0 = 0; k0 < K - 64; k0 += 64) {
    stage(cur ^ 1);
    asm volatile("s_waitcnt vmcnt(8)" ::: "memory");  // cur tile landed
    __builtin_amdgcn_s_barrier();
    asm volatile("" ::: "memory");
    compute(cur);
    asm volatile("" ::: "memory");
    __builtin_amdgcn_s_barrier();                      // all done reading cur
    asm volatile("" ::: "memory");
    cur ^= 1;
  }
  asm volatile("s_waitcnt vmcnt(0)" ::: "memory");
  __builtin_amdgcn_s_barrier();
  asm volatile("" ::: "memory");
  compute(cur);

  // epilogue: C/D layout col=lane&15, row=(lane>>4)*4+reg  [m89/m91 verified]
#pragma unroll
  for (int i = 0; i < 4; ++i) {
    const int mrow = m0 + mw + i * 16 + qd * 4;
#pragma unroll
    for (int j = 0; j < 4; ++j) {
      const int ncol = n0 + nw + j * 16 + li;
      float bv = 0.f;
      if (EPI != EPI_ACC_F32) bv = bias[ncol];
#pragma unroll
      for (int r = 0; r < 4; ++r) {
        const size_t off2 = (size_t)(mrow + r) * N + ncol;
        float v = acc[i][j][r] + bv;
        if (EPI == EPI_BIAS_RES_F32) {
          ((float*)out)[off2] = v + (float)R[off2];
        } else if (EPI == EPI_BIAS_GELU) {
          ((bf16*)out)[off2] = (bf16)gelu_erf(v);
        } else if (EPI == EPI_ACC_F32) {
          ((float*)out)[off2] += v;
        } else {
          ((bf16*)out)[off2] = (bf16)v;
        }
      }
    }
  }
}

// ---------------------------------------------------------------------------
// MFMA attention: one block (4 waves) per (sequence, head).
// P padded to PP (16-mult) for tiles; K-dim of PV padded to PK (32-mult).
// ---------------------------------------------------------------------------
template <int P>
__global__ __launch_bounds__(256) void attn_kernel(const bf16* __restrict__ qkv,
                                                   bf16* __restrict__ out) {
  constexpr int PP   = ((P + 15) / 16) * 16;   // 32, 48, 96
  constexpr int PK   = ((PP + 31) / 32) * 32;  // 32, 64, 96
  constexpr int MT   = PP / 16;
  constexpr int SSTR = PP + 2;                 // fp32 words
  constexpr int VSTR = PK + 8;                 // bf16 elems; *2B is 16B-mult
  constexpr int PSTR = PK + 8;

  __shared__ __align__(16) bf16 QK[2 * PP * 64];  // Q | K ; reused as Ps
  __shared__ __align__(16) bf16 Vt[64 * VSTR];
  __shared__ __align__(16) float Sm[PP * SSTR];
  __shared__ float rsum[PP];

  bf16* Qs = QK;
  bf16* Ks = QK + PP * 64;
  bf16* Ps = QK;  // overlays Q/K after S phase (dead by then)

  const int tid  = threadIdx.x;
  const int lane = tid & 63;
  const int wv   = tid >> 6;
  const int li   = lane & 15;
  const int qd   = lane >> 4;
  const int n    = blockIdx.x >> 3;
  const int h    = blockIdx.x & 7;
  const bf16* base = qkv + (size_t)n * P * QKV_D + h * 64;

  // stage Q,K: 16B chunks, slot = c ^ (r&7)
  for (int t = tid; t < P * 8; t += 256) {
    const int r = t >> 3, c = t & 7;
    const bf16x8 qv = *(const bf16x8*)(base + (size_t)r * QKV_D + c * 8);
    const bf16x8 kv = *(const bf16x8*)(base + (size_t)r * QKV_D + 512 + c * 8);
    *(bf16x8*)(Qs + r * 64 + ((c ^ (r & 7)) * 8)) = qv;
    *(bf16x8*)(Ks + r * 64 + ((c ^ (r & 7)) * 8)) = kv;
  }
  // stage V^T
  for (int t = tid; t < P * 8; t += 256) {
    const int j = t % P, dc = t / P;
    const bf16x8 vv = *(const bf16x8*)(base + (size_t)j * QKV_D + 1024 + dc * 8);
#pragma unroll
    for (int u = 0; u < 8; ++u) Vt[(dc * 8 + u) * VSTR + j] = vv[u];
  }
  if constexpr (PK > P) {
    for (int t = tid; t < 64 * (PK - P); t += 256) {
      const int d = t / (PK - P), j = P + t % (PK - P);
      Vt[d * VSTR + j] = (bf16)0.f;
    }
  }
  __syncthreads();

  // S = Q K^T
  for (int t = wv; t < MT * MT; t += 4) {
    const int ti = t / MT, tj = t % MT;
    f32x4 acc = (f32x4){0.f, 0.f, 0.f, 0.f};
#pragma unroll
    for (int ks = 0; ks < 2; ++ks) {
      const int ck = ks * 4 + qd;
      const int ar = ti * 16 + li;
      const int br = tj * 16 + li;
      const bf16x8 af = *(const bf16x8*)(Qs + ar * 64 + ((ck ^ (ar & 7)) * 8));
      const bf16x8 bv = *(const bf16x8*)(Ks + br * 64 + ((ck ^ (br & 7)) * 8));
      acc = __builtin_amdgcn_mfma_f32_16x16x32_bf16(af, bv, acc, 0, 0, 0);
    }
#pragma unroll
    for (int r = 0; r < 4; ++r)
      Sm[(ti * 16 + qd * 4 + r) * SSTR + tj * 16 + li] = acc[r];
  }
  __syncthreads();

  // softmax row: unnormalized exp -> bf16 Ps; 1/sum saved for O-write
  if (tid < P) {
    const float* srow = Sm + tid * SSTR;
    bf16* prow = Ps + tid * PSTR;
    float mx = -1e30f;
    for (int j = 0; j < P; ++j) mx = fmaxf(mx, srow[j]);
    mx *= 0.125f;  // 1/sqrt(64)
    float sum = 0.f;
    for (int j = 0; j < P; ++j) {
      const float e = __expf(srow[j] * 0.125f - mx);
      sum += e;
      prow[j] = (bf16)e;
    }
    for (int j = P; j < PK; ++j) prow[j] = (bf16)0.f;
    rsum[tid] = 1.f / sum;
  }
  __syncthreads();

  // O = P V
  for (int t = wv; t < MT * 4; t += 4) {
    const int ti = t >> 2, td = t & 3;
    f32x4 acc = (f32x4){0.f, 0.f, 0.f, 0.f};
#pragma unroll
    for (int ks = 0; ks < PK / 32; ++ks) {
      const int ck = ks * 4 + qd;
      const bf16x8 af = *(const bf16x8*)(Ps + (ti * 16 + li) * PSTR + ck * 8);
      const bf16x8 bv = *(const bf16x8*)(Vt + (td * 16 + li) * VSTR + ck * 8);
      acc = __builtin_amdgcn_mfma_f32_16x16x32_bf16(af, bv, acc, 0, 0, 0);
    }
#pragma unroll
    for (int r = 0; r < 4; ++r) {
      const int row = ti * 16 + qd * 4 + r;
      if (row < P)
        out[(size_t)(n * P + row) * HID + h * 64 + td * 16 + li] =
            (bf16)(acc[r] * rsum[row]);
    }
  }
}

// ---------------------------------------------------------------------------
// LayerNorm over 512, one wave per row. float4 loads, bf16x4 stores.
// ---------------------------------------------------------------------------
__global__ __launch_bounds__(256) void ln_kernel(const float* __restrict__ Y,
                                                 const float* __restrict__ w,
                                                 const float* __restrict__ b,
                                                 bf16* __restrict__ X) {
  const int row  = blockIdx.x * 4 + (threadIdx.x >> 6);
  const int lane = threadIdx.x & 63;
  const float4* y4 = (const float4*)(Y + (size_t)row * HID);
  const float4 u = y4[lane];
  const float4 v = y4[lane + 64];
  float s  = u.x + u.y + u.z + u.w + v.x + v.y + v.z + v.w;
  float s2 = u.x*u.x + u.y*u.y + u.z*u.z + u.w*u.w +
             v.x*v.x + v.y*v.y + v.z*v.z + v.w*v.w;
#pragma unroll
  for (int off = 32; off > 0; off >>= 1) {
    s  += __shfl_xor(s, off, 64);
    s2 += __shfl_xor(s2, off, 64);
  }
  const float mean = s * (1.f / 512.f);
  const float var  = s2 * (1.f / 512.f) - mean * mean;
  const float rstd = rsqrtf(var + 1e-5f);
  const float4 w0 = ((const float4*)w)[lane];
  const float4 w1 = ((const float4*)w)[lane + 64];
  const float4 b0 = ((const float4*)b)[lane];
  const float4 b1 = ((const float4*)b)[lane + 64];
  bf16* xr = X + (size_t)row * HID;
  bf16x4 o0 = {(bf16)((u.x - mean) * rstd * w0.x + b0.x),
               (bf16)((u.y - mean) * rstd * w0.y + b0.y),
               (bf16)((u.z - mean) * rstd * w0.z + b0.z),
               (bf16)((u.w - mean) * rstd * w0.w + b0.w)};
  bf16x4 o1 = {(bf16)((v.x - mean) * rstd * w1.x + b1.x),
               (bf16)((v.y - mean) * rstd * w1.y + b1.y),
               (bf16)((v.z - mean) * rstd * w1.z + b1.z),
               (bf16)((v.w - mean) * rstd * w1.w + b1.w)};
  *(bf16x4*)(xr + 4 * lane)       = o0;
  *(bf16x4*)(xr + 256 + 4 * lane) = o1;
}

// ---------------------------------------------------------------------------
// input projection: h[r,o] = sum_k x[r,k]*w[o,k] + b[o], K=7. Writes the same
// value to nbr consecutive [TOKENS,HID] slices (branches share the input).
// ---------------------------------------------------------------------------
__global__ __launch_bounds__(256) void inproj_kernel(const float* __restrict__ x,
                                                     const float* __restrict__ w,
                                                     const float* __restrict__ b,
                                                     bf16* __restrict__ h,
                                                     int nbr) {
  const int idx = blockIdx.x * 256 + threadIdx.x;
  const int r = idx >> 9, o = idx & 511;
  float s = b[o];
#pragma unroll
  for (int k = 0; k < 7; ++k) s += x[r * 7 + k] * w[o * 7 + k];
  const bf16 bv = (bf16)s;
  for (int q = 0; q < nbr; ++q) h[idx + (size_t)q * TOKENS * HID] = bv;
}

// acc[row] (+)= X[row,:] . w  (per-branch final projection accumulate)
__global__ __launch_bounds__(256) void outdot_kernel(const bf16* __restrict__ X,
                                                     const float* __restrict__ w,
                                                     float* __restrict__ acc,
                                                     int first) {
  const int row  = blockIdx.x * 4 + (threadIdx.x >> 6);
  const int lane = threadIdx.x & 63;
  const bf16* xr = X + (size_t)row * HID;
  const bf16x8 xa = *(const bf16x8*)(xr + 8 * lane);
  const float4 wa = ((const float4*)w)[2 * lane];
  const float4 wb = ((const float4*)w)[2 * lane + 1];
  float s = (float)xa[0] * wa.x + (float)xa[1] * wa.y + (float)xa[2] * wa.z +
            (float)xa[3] * wa.w + (float)xa[4] * wb.x + (float)xa[5] * wb.y +
            (float)xa[6] * wb.z + (float)xa[7] * wb.w;
#pragma unroll
  for (int off = 32; off > 0; off >>= 1) s += __shfl_xor(s, off, 64);
  if (lane == 0) acc[row] = first ? s : (acc[row] + s);
}

// out[b,o] = (1/30) * sum_{j<10} acc[b*960 + o*10 + j] + b_out   (fp32 out)
__global__ __launch_bounds__(256) void pool_kernel(const float* __restrict__ acc,
                                                   const float* __restrict__ ob,
                                                   float* __restrict__ out) {
  const int idx = blockIdx.x * 256 + threadIdx.x;
  if (idx >= 16 * 96) return;
  const int bb = idx / 96, o = idx % 96;
  float s = 0.f;
#pragma unroll
  for (int j = 0; j < 10; ++j) s += acc[bb * 960 + o * 10 + j];
  out[idx] = s * (1.f / 30.f) + ob[0];
}

// ---------------------------------------------------------------------------
extern "C" void kernel_launch(void* const* d_in, const int* in_sizes, int n_in,
                              void* d_out, int out_size, void* d_ws,
                              size_t ws_size, hipStream_t stream) {
  const float* x          = (const float*)d_in[0];
  const float* ip_w       = (const float*)d_in[1];
  const float* ip_b       = (const float*)d_in[2];
  const float* in_proj_w  = (const float*)d_in[3];
  const float* in_proj_b  = (const float*)d_in[4];
  const float* out_proj_w = (const float*)d_in[5];
  const float* out_proj_b = (const float*)d_in[6];
  const float* ffn_w1     = (const float*)d_in[7];
  const float* ffn_b1     = (const float*)d_in[8];
  const float* ffn_w2     = (const float*)d_in[9];
  const float* ffn_b2     = (const float*)d_in[10];
  const float* ln1_w      = (const float*)d_in[11];
  const float* ln1_b      = (const float*)d_in[12];
  const float* ln2_w      = (const float*)d_in[13];
  const float* ln2_b      = (const float*)d_in[14];
  const float* op_w       = (const float*)d_in[15];
  const float* op_b       = (const float*)d_in[16];

  // fixed carve: weights + ACC, then activations (path-dependent)
  char* p = (char*)d_ws;
  bf16* Wq  = (bf16*)p; p += (size_t)4 * QKV_D * HID * 2;
  bf16* Wo  = (bf16*)p; p += (size_t)4 * HID * HID * 2;
  bf16* W1  = (bf16*)p; p += (size_t)4 * FFN_D * HID * 2;
  bf16* W2s = (bf16*)p; p += (size_t)4 * HID * FFN_D * 2;  // split layout
  float* ACC = (float*)p; p += (size_t)TOKENS * 4;
  const size_t remain = ws_size - (size_t)(p - (char*)d_ws);

  const size_t T3 = 3 * (size_t)TOKENS;
  // batched: X bf16 [T3,512] + BUF bf16 [T3,2048]; inside BUF, by liveness:
  //   QKV [0,1536) | ATT [1536,2048)     (attention phase)
  //   Y0 fp32 [0,1024)                   (Wo out -> LN1; QKV region dead)
  //   H bf16 [0,1024) | Y2 fp32 [1024,2048)  (FFN halves; ATT dead)
  const size_t need_batched = T3 * HID * 2 + T3 * (size_t)FFN_D * 2;  // ~236 MB
  const size_t need_seq =
      (size_t)TOKENS * HID * 4 + (size_t)TOKENS * HID * 2 +
      (size_t)TOKENS * FFN_D * 2;                                     // ~110 MB
  const bool batched = remain >= need_batched;
  if (!batched && remain < need_seq) return;

  {  // weight conversion fp32 -> bf16
    const int nq = 4 * QKV_D * HID / 4, no = 4 * HID * HID / 4,
              n1 = 4 * FFN_D * HID / 4, n2 = 4 * HID * FFN_D / 4;
    cvt_kernel<<<(nq + 255) / 256, 256, 0, stream>>>(in_proj_w, Wq, nq);
    cvt_kernel<<<(no + 255) / 256, 256, 0, stream>>>(out_proj_w, Wo, no);
    cvt_kernel<<<(n1 + 255) / 256, 256, 0, stream>>>(ffn_w1, W1, n1);
    cvt_w2_kernel<<<(n2 + 255) / 256, 256, 0, stream>>>(ffn_w2, W2s, n2);
  }

  static const int periods[3] = {24, 48, 96};
  auto launch_attn = [&](int P, const bf16* q, bf16* o) {
    const int nblk = (TOKENS / P) * 8;
    if (P == 24)      attn_kernel<24><<<nblk, 256, 0, stream>>>(q, o);
    else if (P == 48) attn_kernel<48><<<nblk, 256, 0, stream>>>(q, o);
    else              attn_kernel<96><<<nblk, 256, 0, stream>>>(q, o);
  };

  // one transformer layer on M rows; buffers per the liveness overlay above
  auto run_layer = [&](int l, int M, bf16* X, bf16* QKV, bf16* ATT,
                       float* Y0, bf16* H, float* Y2, bool all_br, int br) {
    const int MB = M / 128;   // grid = (N/128, M/128), n-fastest in-kernel
    gemm_bt<EPI_BIAS_BF16><<<dim3(QKV_D / 128, MB), 256, 0, stream>>>(
        X, Wq + (size_t)l * QKV_D * HID, in_proj_b + l * QKV_D, nullptr,
        QKV, M, QKV_D, HID);
    if (all_br) {
      for (int b2 = 0; b2 < 3; ++b2)
        launch_attn(periods[b2], QKV + (size_t)b2 * TOKENS * QKV_D,
                    ATT + (size_t)b2 * TOKENS * HID);
    } else {
      launch_attn(periods[br], QKV, ATT);
    }
    gemm_bt<EPI_BIAS_RES_F32><<<dim3(HID / 128, MB), 256, 0, stream>>>(
        ATT, Wo + (size_t)l * HID * HID, out_proj_b + l * HID, X, Y0,
        M, HID, HID);
    ln_kernel<<<M / 4, 256, 0, stream>>>(Y0, ln1_w + l * HID, ln1_b + l * HID, X);
    // FFN split into two K=1024 halves (W2 pre-split so rows are contiguous)
    gemm_bt<EPI_BIAS_GELU><<<dim3(1024 / 128, MB), 256, 0, stream>>>(
        X, W1 + (size_t)l * FFN_D * HID, ffn_b1 + l * FFN_D, nullptr,
        H, M, 1024, HID);
    gemm_bt<EPI_BIAS_RES_F32><<<dim3(HID / 128, MB), 256, 0, stream>>>(
        H, W2s + (size_t)(l * 2 + 0) * HID * 1024, ffn_b2 + l * HID, X, Y2,
        M, HID, 1024);
    gemm_bt<EPI_BIAS_GELU><<<dim3(1024 / 128, MB), 256, 0, stream>>>(
        X, W1 + (size_t)l * FFN_D * HID + (size_t)1024 * HID,
        ffn_b1 + l * FFN_D + 1024, nullptr, H, M, 1024, HID);
    gemm_bt<EPI_ACC_F32><<<dim3(HID / 128, MB), 256, 0, stream>>>(
        H, W2s + (size_t)(l * 2 + 1) * HID * 1024, nullptr, nullptr, Y2,
        M, HID, 1024);
    ln_kernel<<<M / 4, 256, 0, stream>>>(Y2, ln2_w + l * HID, ln2_b + l * HID, X);
  };

  if (batched) {
    bf16* X   = (bf16*)p; p += T3 * HID * 2;
    bf16* BUF = (bf16*)p;
    bf16*  QKV = BUF;
    bf16*  ATT = BUF + T3 * QKV_D;
    float* Y0  = (float*)BUF;
    bf16*  H   = BUF;
    float* Y2  = (float*)(BUF + T3 * 1024);
    const int M = (int)T3;

    inproj_kernel<<<TOKENS * HID / 256, 256, 0, stream>>>(x, ip_w, ip_b, X, 3);
    for (int l = 0; l < 4; ++l)
      run_layer(l, M, X, QKV, ATT, Y0, H, Y2, true, 0);
    for (int br = 0; br < 3; ++br)
      outdot_kernel<<<TOKENS / 4, 256, 0, stream>>>(
          X + (size_t)br * TOKENS * HID, op_w, ACC, br == 0);
  } else {
    // sequential (fits in ~135 MB)
    float* Y  = (float*)p; p += (size_t)TOKENS * HID * 4;
    bf16* X   = (bf16*)p;  p += (size_t)TOKENS * HID * 2;
    bf16* SCR = (bf16*)p;  p += (size_t)TOKENS * FFN_D * 2;
    bf16*  QKV = SCR;
    bf16*  ATT = SCR + (size_t)TOKENS * QKV_D;
    bf16*  H   = SCR;   // reuses QKV region (dead after attention)
    const int M = TOKENS;

    for (int br = 0; br < 3; ++br) {
      inproj_kernel<<<TOKENS * HID / 256, 256, 0, stream>>>(x, ip_w, ip_b, X, 1);
      for (int l = 0; l < 4; ++l)
        run_layer(l, M, X, QKV, ATT, Y, H, Y, false, br);
      outdot_kernel<<<TOKENS / 4, 256, 0, stream>>>(X, op_w, ACC, br == 0);
    }
  }
  pool_kernel<<<6, 256, 0, stream>>>(ACC, op_b, (float*)d_out);
}

// Round 6
// 2202.987 us; speedup vs baseline: 1.3814x; 1.0862x over previous
//
#include <hip/hip_runtime.h>
#include <hip/hip_bf16.h>

typedef __bf16 bf16;
typedef __attribute__((ext_vector_type(8))) __bf16 bf16x8;
typedef __attribute__((ext_vector_type(4))) __bf16 bf16x4;
typedef __attribute__((ext_vector_type(4))) float f32x4;

#define TOKENS 15360   // B*S = 16*960
#define HID    512
#define FFN_D  2048
#define QKV_D  1536

// ---------------------------------------------------------------------------
// fast exact-GELU: A&S 7.1.26 erf (|eps|<=1.5e-7), hw exp + hw rcp
// ---------------------------------------------------------------------------
__device__ __forceinline__ float gelu_erf(float x) {
  const float z = fabsf(x) * 0.70710678118654752f;
#if __has_builtin(__builtin_amdgcn_rcpf)
  const float t = __builtin_amdgcn_rcpf(fmaf(0.3275911f, z, 1.f));
#else
  const float t = 1.f / fmaf(0.3275911f, z, 1.f);
#endif
  float p = fmaf(1.061405429f, t, -1.453152027f);
  p = fmaf(p, t, 1.421413741f);
  p = fmaf(p, t, -0.284496736f);
  p = fmaf(p, t, 0.254829592f);
  p *= t;
  const float e  = __expf(-z * z);
  const float er = fmaf(-p, e, 1.f);          // erf(|x|/sqrt2)
  return 0.5f * x * (1.f + copysignf(er, x));
}

// ---------------------------------------------------------------------------
// fp32 -> bf16 weight conversion (run every launch; ws is re-poisoned)
// ---------------------------------------------------------------------------
__global__ __launch_bounds__(256) void cvt_kernel(const float* __restrict__ src,
                                                  bf16* __restrict__ dst, int n4) {
  const int i = (blockIdx.x * 256 + threadIdx.x);
  if (i >= n4) return;
  const float4 v = ((const float4*)src)[i];
  bf16x4 d = {(bf16)v.x, (bf16)v.y, (bf16)v.z, (bf16)v.w};
  *(bf16x4*)(dst + (size_t)i * 4) = d;
}

// W2 [4][512][2048] fp32 -> split bf16 [4][2][512][1024]:
// dst[l][h][n][c] = src[l][n][h*1024+c]  (so each K=1024 half has contiguous rows)
__global__ __launch_bounds__(256) void cvt_w2_kernel(const float* __restrict__ src,
                                                     bf16* __restrict__ dst, int n4) {
  const int i = (blockIdx.x * 256 + threadIdx.x);
  if (i >= n4) return;
  const int f  = i * 4;
  const int ln = f >> 11;        // l*512 + n
  const int c2 = f & 2047;
  const int h  = c2 >> 10;
  const int c  = c2 & 1023;
  const int l  = ln >> 9;
  const int n  = ln & 511;
  const float4 v = ((const float4*)src)[i];
  bf16x4 d = {(bf16)v.x, (bf16)v.y, (bf16)v.z, (bf16)v.w};
  *(bf16x4*)(dst + ((((size_t)(l * 2 + h) * 512 + n) << 10) + c)) = d;
}

// ---------------------------------------------------------------------------
// GEMM: C[M,N] = A[M,K] @ W[N,K]^T (+bias fp32, + optional residual / GELU).
// 128x128 tile, BK=64, 4 waves, each 64x64 via 4x4 mfma_f32_16x16x32_bf16.
// Double-buffered LDS, 2-phase pipeline (round-1 schedule, best measured):
//   prologue STAGE(buf0);
//   loop { STAGE(buf^1); s_waitcnt vmcnt(8); s_barrier; compute(buf); s_barrier }
// Counted vmcnt(8) = next tile's 8 loads stay in flight; in-order VMEM
// retirement => current tile landed. Only the last K-tile drains vmcnt(0).
// grid = (N/128, M/128) with XCD-chunked, n-fastest logical ordering
// (round-5 verified: FETCH 237->104 MB, QKV 584->~670 TF).
// XOR swizzle (slot c holds k-chunk c^(r&7)) keeps async-copy contiguity AND
// makes ds_read_b128 2-way (free, measured 0 conflicts).
// All epilogues write bf16 (round 6): residual read is bf16, one touch per
// element => in-place out==R is safe.
// ---------------------------------------------------------------------------
#define EPI_BIAS_BF16     0   // out = v
#define EPI_BIAS_RES_BF16 1   // out = v + R
#define EPI_BIAS_GELU     2   // out = gelu(v)
#define EPI_RES_BF16      3   // out = acc + R   (no bias)

template <int EPI>
__global__ __launch_bounds__(256) void gemm_bt(
    const bf16* __restrict__ A, const bf16* __restrict__ W,
    const float* __restrict__ bias, const bf16* __restrict__ R,
    bf16* __restrict__ out, int M, int N, int K) {
  __shared__ __align__(16) bf16 As[2 * 128 * 64];
  __shared__ __align__(16) bf16 Bs[2 * 128 * 64];

  const int tid  = threadIdx.x;
  const int lane = tid & 63;
  const int wv   = tid >> 6;
  const int li   = lane & 15;
  const int qd   = lane >> 4;
  const int mw   = (wv & 1) << 6;
  const int nw   = (wv >> 1) << 6;

  // XCD-chunked, n-fastest logical ordering. grid = (NB = N/128, MB = M/128).
  const int NB  = gridDim.x;
  const int nwg = NB * gridDim.y;
  int lid = blockIdx.y * NB + blockIdx.x;
  if ((nwg & 7) == 0) lid = (lid & 7) * (nwg >> 3) + (lid >> 3);
  const int n0 = (lid % NB) << 7;
  const int m0 = (lid / NB) << 7;

  f32x4 acc[4][4];
#pragma unroll
  for (int i = 0; i < 4; ++i)
#pragma unroll
    for (int j = 0; j < 4; ++j) acc[i][j] = (f32x4){0.f, 0.f, 0.f, 0.f};

  // staging addresses: tid-invariant parts hoisted; pointers advance by BK
  const bf16* pa[4];
  const bf16* pb[4];
  int off[4];
#pragma unroll
  for (int it = 0; it < 4; ++it) {
    const int fc   = it * 256 + tid;
    const int r    = fc >> 3;
    const int c    = fc & 7;
    const int koff = (c ^ (r & 7)) << 3;
    pa[it]  = A + (size_t)(m0 + r) * K + koff;
    pb[it]  = W + (size_t)(n0 + r) * K + koff;
    off[it] = (it * 256 + (tid & 192)) * 8;  // wave-uniform LDS base (elems)
  }

  auto stage = [&](int buf) {   // 8 global_load_lds per thread (4 A + 4 B)
#pragma unroll
    for (int it = 0; it < 4; ++it) {
      __builtin_amdgcn_global_load_lds(
          (const __attribute__((address_space(1))) unsigned int*)pa[it],
          (__attribute__((address_space(3))) unsigned int*)(As + buf * 8192 + off[it]),
          16, 0, 0);
      pa[it] += 64;
    }
#pragma unroll
    for (int it = 0; it < 4; ++it) {
      __builtin_amdgcn_global_load_lds(
          (const __attribute__((address_space(1))) unsigned int*)pb[it],
          (__attribute__((address_space(3))) unsigned int*)(Bs + buf * 8192 + off[it]),
          16, 0, 0);
      pb[it] += 64;
    }
  };

  auto compute = [&](int buf) {
    const bf16* Ab = As + buf * 8192;
    const bf16* Bb = Bs + buf * 8192;
#pragma unroll
    for (int ks = 0; ks < 2; ++ks) {
      const int ck = (ks << 2) + qd;         // A/B frag: k-chunk = quad (+4*ks)
      bf16x8 af[4], bfv[4];
#pragma unroll
      for (int i = 0; i < 4; ++i) {
        const int mr = mw + i * 16 + li;     // mr&7 == li&7
        af[i] = *(const bf16x8*)(Ab + mr * 64 + ((ck ^ (li & 7)) << 3));
      }
#pragma unroll
      for (int j = 0; j < 4; ++j) {
        const int nr = nw + j * 16 + li;
        bfv[j] = *(const bf16x8*)(Bb + nr * 64 + ((ck ^ (li & 7)) << 3));
      }
#pragma unroll
      for (int i = 0; i < 4; ++i)
#pragma unroll
        for (int j = 0; j < 4; ++j)
          acc[i][j] = __builtin_amdgcn_mfma_f32_16x16x32_bf16(af[i], bfv[j],
                                                              acc[i][j], 0, 0, 0);
    }
  };

  stage(0);
  int cur = 0;
  for (int k0 = 0; k0 < K - 64; k0 += 64) {
    stage(cur ^ 1);
    asm volatile("s_waitcnt vmcnt(8)" ::: "memory");  // cur tile landed
    __builtin_amdgcn_s_barrier();
    asm volatile("" ::: "memory");
    compute(cur);
    asm volatile("" ::: "memory");
    __builtin_amdgcn_s_barrier();                      // all done reading cur
    asm volatile("" ::: "memory");
    cur ^= 1;
  }
  asm volatile("s_waitcnt vmcnt(0)" ::: "memory");
  __builtin_amdgcn_s_barrier();
  asm volatile("" ::: "memory");
  compute(cur);

  // epilogue: C/D layout col=lane&15, row=(lane>>4)*4+reg  [m89/m91 verified]
#pragma unroll
  for (int i = 0; i < 4; ++i) {
    const int mrow = m0 + mw + i * 16 + qd * 4;
#pragma unroll
    for (int j = 0; j < 4; ++j) {
      const int ncol = n0 + nw + j * 16 + li;
      float bv = 0.f;
      if (EPI != EPI_RES_BF16) bv = bias[ncol];
#pragma unroll
      for (int r = 0; r < 4; ++r) {
        const size_t off2 = (size_t)(mrow + r) * N + ncol;
        float v = acc[i][j][r] + bv;
        if (EPI == EPI_BIAS_RES_BF16 || EPI == EPI_RES_BF16) v += (float)R[off2];
        out[off2] = (EPI == EPI_BIAS_GELU) ? (bf16)gelu_erf(v) : (bf16)v;
      }
    }
  }
}

// ---------------------------------------------------------------------------
// MFMA attention: one block (4 waves) per (sequence, head).
// P padded to PP (16-mult) for tiles; K-dim of PV padded to PK (32-mult).
// Softmax is group-parallel (G lanes per row, shfl_xor reduce) -- round 6.
// ---------------------------------------------------------------------------
template <int P>
__global__ __launch_bounds__(256) void attn_kernel(const bf16* __restrict__ qkv,
                                                   bf16* __restrict__ out) {
  constexpr int PP   = ((P + 15) / 16) * 16;   // 32, 48, 96
  constexpr int PK   = ((PP + 31) / 32) * 32;  // 32, 64, 96
  constexpr int MT   = PP / 16;
  constexpr int SSTR = PP + 2;                 // fp32 words
  constexpr int VSTR = PK + 8;                 // bf16 elems; *2B is 16B-mult
  constexpr int PSTR = PK + 8;
  constexpr int G    = (P * 8 <= 256) ? 8 : ((P * 4 <= 256) ? 4 : 2);

  __shared__ __align__(16) bf16 QK[2 * PP * 64];  // Q | K ; reused as Ps
  __shared__ __align__(16) bf16 Vt[64 * VSTR];
  __shared__ __align__(16) float Sm[PP * SSTR];
  __shared__ float rsum[PP];

  bf16* Qs = QK;
  bf16* Ks = QK + PP * 64;
  bf16* Ps = QK;  // overlays Q/K after S phase (dead by then)

  const int tid  = threadIdx.x;
  const int lane = tid & 63;
  const int wv   = tid >> 6;
  const int li   = lane & 15;
  const int qd   = lane >> 4;
  const int n    = blockIdx.x >> 3;
  const int h    = blockIdx.x & 7;
  const bf16* base = qkv + (size_t)n * P * QKV_D + h * 64;

  // stage Q,K: 16B chunks, slot = c ^ (r&7)
  for (int t = tid; t < P * 8; t += 256) {
    const int r = t >> 3, c = t & 7;
    const bf16x8 qv = *(const bf16x8*)(base + (size_t)r * QKV_D + c * 8);
    const bf16x8 kv = *(const bf16x8*)(base + (size_t)r * QKV_D + 512 + c * 8);
    *(bf16x8*)(Qs + r * 64 + ((c ^ (r & 7)) * 8)) = qv;
    *(bf16x8*)(Ks + r * 64 + ((c ^ (r & 7)) * 8)) = kv;
  }
  // stage V^T
  for (int t = tid; t < P * 8; t += 256) {
    const int j = t % P, dc = t / P;
    const bf16x8 vv = *(const bf16x8*)(base + (size_t)j * QKV_D + 1024 + dc * 8);
#pragma unroll
    for (int u = 0; u < 8; ++u) Vt[(dc * 8 + u) * VSTR + j] = vv[u];
  }
  if constexpr (PK > P) {
    for (int t = tid; t < 64 * (PK - P); t += 256) {
      const int d = t / (PK - P), j = P + t % (PK - P);
      Vt[d * VSTR + j] = (bf16)0.f;
    }
  }
  __syncthreads();

  // S = Q K^T
  for (int t = wv; t < MT * MT; t += 4) {
    const int ti = t / MT, tj = t % MT;
    f32x4 acc = (f32x4){0.f, 0.f, 0.f, 0.f};
#pragma unroll
    for (int ks = 0; ks < 2; ++ks) {
      const int ck = ks * 4 + qd;
      const int ar = ti * 16 + li;
      const int br = tj * 16 + li;
      const bf16x8 af = *(const bf16x8*)(Qs + ar * 64 + ((ck ^ (ar & 7)) * 8));
      const bf16x8 bv = *(const bf16x8*)(Ks + br * 64 + ((ck ^ (br & 7)) * 8));
      acc = __builtin_amdgcn_mfma_f32_16x16x32_bf16(af, bv, acc, 0, 0, 0);
    }
#pragma unroll
    for (int r = 0; r < 4; ++r)
      Sm[(ti * 16 + qd * 4 + r) * SSTR + tj * 16 + li] = acc[r];
  }
  __syncthreads();

  // softmax: G lanes per row (G|64, groups lane-aligned so shfl_xor stays
  // in-group). unnormalized exp -> bf16 Ps; 1/sum saved for O-write.
  if (tid < P * G) {
    const int row = tid / G, g = tid % G;
    const float* srow = Sm + row * SSTR;
    bf16* prow = Ps + row * PSTR;
    float mx = -1e30f;
    for (int j = g; j < P; j += G) mx = fmaxf(mx, srow[j]);
#pragma unroll
    for (int m = G >> 1; m; m >>= 1) mx = fmaxf(mx, __shfl_xor(mx, m, 64));
    mx *= 0.125f;  // 1/sqrt(64)
    float sum = 0.f;
    for (int j = g; j < P; j += G) {
      const float e = __expf(srow[j] * 0.125f - mx);
      sum += e;
      prow[j] = (bf16)e;
    }
#pragma unroll
    for (int m = G >> 1; m; m >>= 1) sum += __shfl_xor(sum, m, 64);
    for (int j = P + g; j < PK; j += G) prow[j] = (bf16)0.f;
    if (g == 0) rsum[row] = 1.f / sum;
  }
  __syncthreads();

  // O = P V
  for (int t = wv; t < MT * 4; t += 4) {
    const int ti = t >> 2, td = t & 3;
    f32x4 acc = (f32x4){0.f, 0.f, 0.f, 0.f};
#pragma unroll
    for (int ks = 0; ks < PK / 32; ++ks) {
      const int ck = ks * 4 + qd;
      const bf16x8 af = *(const bf16x8*)(Ps + (ti * 16 + li) * PSTR + ck * 8);
      const bf16x8 bv = *(const bf16x8*)(Vt + (td * 16 + li) * VSTR + ck * 8);
      acc = __builtin_amdgcn_mfma_f32_16x16x32_bf16(af, bv, acc, 0, 0, 0);
    }
#pragma unroll
    for (int r = 0; r < 4; ++r) {
      const int row = ti * 16 + qd * 4 + r;
      if (row < P)
        out[(size_t)(n * P + row) * HID + h * 64 + td * 16 + li] =
            (bf16)(acc[r] * rsum[row]);
    }
  }
}

// ---------------------------------------------------------------------------
// LayerNorm over 512, one wave per row. bf16x8 loads (round 6: pre-LN sum is
// stored bf16 by the GEMM epilogue), bf16x8 stores.
// ---------------------------------------------------------------------------
__global__ __launch_bounds__(256) void ln_kernel(const bf16* __restrict__ Y,
                                                 const float* __restrict__ w,
                                                 const float* __restrict__ b,
                                                 bf16* __restrict__ X) {
  const int row  = blockIdx.x * 4 + (threadIdx.x >> 6);
  const int lane = threadIdx.x & 63;
  const bf16x8 yv = *(const bf16x8*)(Y + (size_t)row * HID + 8 * lane);
  float y[8];
#pragma unroll
  for (int u = 0; u < 8; ++u) y[u] = (float)yv[u];
  float s = 0.f, s2 = 0.f;
#pragma unroll
  for (int u = 0; u < 8; ++u) { s += y[u]; s2 += y[u] * y[u]; }
#pragma unroll
  for (int off = 32; off > 0; off >>= 1) {
    s  += __shfl_xor(s, off, 64);
    s2 += __shfl_xor(s2, off, 64);
  }
  const float mean = s * (1.f / 512.f);
  const float var  = s2 * (1.f / 512.f) - mean * mean;
  const float rstd = rsqrtf(var + 1e-5f);
  const float4 w0 = ((const float4*)w)[2 * lane];
  const float4 w1 = ((const float4*)w)[2 * lane + 1];
  const float4 b0 = ((const float4*)b)[2 * lane];
  const float4 b1 = ((const float4*)b)[2 * lane + 1];
  const float wr[8] = {w0.x, w0.y, w0.z, w0.w, w1.x, w1.y, w1.z, w1.w};
  const float br[8] = {b0.x, b0.y, b0.z, b0.w, b1.x, b1.y, b1.z, b1.w};
  bf16x8 o;
#pragma unroll
  for (int u = 0; u < 8; ++u) o[u] = (bf16)((y[u] - mean) * rstd * wr[u] + br[u]);
  *(bf16x8*)(X + (size_t)row * HID + 8 * lane) = o;
}

// ---------------------------------------------------------------------------
// input projection: h[r,o] = sum_k x[r,k]*w[o,k] + b[o], K=7. Writes the same
// value to nbr consecutive [TOKENS,HID] slices (branches share the input).
// ---------------------------------------------------------------------------
__global__ __launch_bounds__(256) void inproj_kernel(const float* __restrict__ x,
                                                     const float* __restrict__ w,
                                                     const float* __restrict__ b,
                                                     bf16* __restrict__ h,
                                                     int nbr) {
  const int idx = blockIdx.x * 256 + threadIdx.x;
  const int r = idx >> 9, o = idx & 511;
  float s = b[o];
#pragma unroll
  for (int k = 0; k < 7; ++k) s += x[r * 7 + k] * w[o * 7 + k];
  const bf16 bv = (bf16)s;
  for (int q = 0; q < nbr; ++q) h[idx + (size_t)q * TOKENS * HID] = bv;
}

// acc[row] (+)= X[row,:] . w  (per-branch final projection accumulate)
__global__ __launch_bounds__(256) void outdot_kernel(const bf16* __restrict__ X,
                                                     const float* __restrict__ w,
                                                     float* __restrict__ acc,
                                                     int first) {
  const int row  = blockIdx.x * 4 + (threadIdx.x >> 6);
  const int lane = threadIdx.x & 63;
  const bf16* xr = X + (size_t)row * HID;
  const bf16x8 xa = *(const bf16x8*)(xr + 8 * lane);
  const float4 wa = ((const float4*)w)[2 * lane];
  const float4 wb = ((const float4*)w)[2 * lane + 1];
  float s = (float)xa[0] * wa.x + (float)xa[1] * wa.y + (float)xa[2] * wa.z +
            (float)xa[3] * wa.w + (float)xa[4] * wb.x + (float)xa[5] * wb.y +
            (float)xa[6] * wb.z + (float)xa[7] * wb.w;
#pragma unroll
  for (int off = 32; off > 0; off >>= 1) s += __shfl_xor(s, off, 64);
  if (lane == 0) acc[row] = first ? s : (acc[row] + s);
}

// out[b,o] = (1/30) * sum_{j<10} acc[b*960 + o*10 + j] + b_out   (fp32 out)
__global__ __launch_bounds__(256) void pool_kernel(const float* __restrict__ acc,
                                                   const float* __restrict__ ob,
                                                   float* __restrict__ out) {
  const int idx = blockIdx.x * 256 + threadIdx.x;
  if (idx >= 16 * 96) return;
  const int bb = idx / 96, o = idx % 96;
  float s = 0.f;
#pragma unroll
  for (int j = 0; j < 10; ++j) s += acc[bb * 960 + o * 10 + j];
  out[idx] = s * (1.f / 30.f) + ob[0];
}

// ---------------------------------------------------------------------------
extern "C" void kernel_launch(void* const* d_in, const int* in_sizes, int n_in,
                              void* d_out, int out_size, void* d_ws,
                              size_t ws_size, hipStream_t stream) {
  const float* x          = (const float*)d_in[0];
  const float* ip_w       = (const float*)d_in[1];
  const float* ip_b       = (const float*)d_in[2];
  const float* in_proj_w  = (const float*)d_in[3];
  const float* in_proj_b  = (const float*)d_in[4];
  const float* out_proj_w = (const float*)d_in[5];
  const float* out_proj_b = (const float*)d_in[6];
  const float* ffn_w1     = (const float*)d_in[7];
  const float* ffn_b1     = (const float*)d_in[8];
  const float* ffn_w2     = (const float*)d_in[9];
  const float* ffn_b2     = (const float*)d_in[10];
  const float* ln1_w      = (const float*)d_in[11];
  const float* ln1_b      = (const float*)d_in[12];
  const float* ln2_w      = (const float*)d_in[13];
  const float* ln2_b      = (const float*)d_in[14];
  const float* op_w       = (const float*)d_in[15];
  const float* op_b       = (const float*)d_in[16];

  // fixed carve: weights + ACC, then activations (path-dependent)
  char* p = (char*)d_ws;
  bf16* Wq  = (bf16*)p; p += (size_t)4 * QKV_D * HID * 2;
  bf16* Wo  = (bf16*)p; p += (size_t)4 * HID * HID * 2;
  bf16* W1  = (bf16*)p; p += (size_t)4 * FFN_D * HID * 2;
  bf16* W2s = (bf16*)p; p += (size_t)4 * HID * FFN_D * 2;  // split layout
  float* ACC = (float*)p; p += (size_t)TOKENS * 4;
  const size_t remain = ws_size - (size_t)(p - (char*)d_ws);

  const size_t T3 = 3 * (size_t)TOKENS;
  // batched: X bf16 [T3,512] + BUF bf16 slabs (T3*2048 elems), by liveness:
  //   QKV slab [0, T3*1536)   | ATT slab [T3*1536, T3*2048)   (attention)
  //   H slab   [0, T3*1024)   | YB slab  [T3*1024, T3*1536)   (LN chain; YB
  //   inside the dead QKV slab, disjoint from H and ATT). No fp32 Y anymore.
  const size_t need_batched = T3 * HID * 2 + T3 * (size_t)FFN_D * 2;  // ~236 MB
  const size_t need_seq =
      (size_t)TOKENS * HID * 2 + (size_t)TOKENS * FFN_D * 2;          // ~79 MB
  const bool batched = remain >= need_batched;
  if (!batched && remain < need_seq) return;

  {  // weight conversion fp32 -> bf16
    const int nq = 4 * QKV_D * HID / 4, no = 4 * HID * HID / 4,
              n1 = 4 * FFN_D * HID / 4, n2 = 4 * HID * FFN_D / 4;
    cvt_kernel<<<(nq + 255) / 256, 256, 0, stream>>>(in_proj_w, Wq, nq);
    cvt_kernel<<<(no + 255) / 256, 256, 0, stream>>>(out_proj_w, Wo, no);
    cvt_kernel<<<(n1 + 255) / 256, 256, 0, stream>>>(ffn_w1, W1, n1);
    cvt_w2_kernel<<<(n2 + 255) / 256, 256, 0, stream>>>(ffn_w2, W2s, n2);
  }

  static const int periods[3] = {24, 48, 96};
  auto launch_attn = [&](int P, const bf16* q, bf16* o) {
    const int nblk = (TOKENS / P) * 8;
    if (P == 24)      attn_kernel<24><<<nblk, 256, 0, stream>>>(q, o);
    else if (P == 48) attn_kernel<48><<<nblk, 256, 0, stream>>>(q, o);
    else              attn_kernel<96><<<nblk, 256, 0, stream>>>(q, o);
  };

  // one transformer layer on M rows; buffers per the liveness overlay above
  auto run_layer = [&](int l, int M, bf16* X, bf16* QKV, bf16* ATT, bf16* YB,
                       bf16* H, bool all_br, int br) {
    const int MB = M / 128;   // grid = (N/128, M/128), n-fastest in-kernel
    gemm_bt<EPI_BIAS_BF16><<<dim3(QKV_D / 128, MB), 256, 0, stream>>>(
        X, Wq + (size_t)l * QKV_D * HID, in_proj_b + l * QKV_D, nullptr,
        QKV, M, QKV_D, HID);
    if (all_br) {
      for (int b2 = 0; b2 < 3; ++b2)
        launch_attn(periods[b2], QKV + (size_t)b2 * TOKENS * QKV_D,
                    ATT + (size_t)b2 * TOKENS * HID);
    } else {
      launch_attn(periods[br], QKV, ATT);
    }
    // pre-LN sum written bf16 (round 6): saves the fp32 Y round-trip
    gemm_bt<EPI_BIAS_RES_BF16><<<dim3(HID / 128, MB), 256, 0, stream>>>(
        ATT, Wo + (size_t)l * HID * HID, out_proj_b + l * HID, X, YB,
        M, HID, HID);
    ln_kernel<<<M / 4, 256, 0, stream>>>(YB, ln1_w + l * HID, ln1_b + l * HID, X);
    // FFN split into two K=1024 halves (W2 pre-split so rows are contiguous)
    gemm_bt<EPI_BIAS_GELU><<<dim3(1024 / 128, MB), 256, 0, stream>>>(
        X, W1 + (size_t)l * FFN_D * HID, ffn_b1 + l * FFN_D, nullptr,
        H, M, 1024, HID);
    gemm_bt<EPI_BIAS_RES_BF16><<<dim3(HID / 128, MB), 256, 0, stream>>>(
        H, W2s + (size_t)(l * 2 + 0) * HID * 1024, ffn_b2 + l * HID, X, YB,
        M, HID, 1024);
    gemm_bt<EPI_BIAS_GELU><<<dim3(1024 / 128, MB), 256, 0, stream>>>(
        X, W1 + (size_t)l * FFN_D * HID + (size_t)1024 * HID,
        ffn_b1 + l * FFN_D + 1024, nullptr, H, M, 1024, HID);
    gemm_bt<EPI_RES_BF16><<<dim3(HID / 128, MB), 256, 0, stream>>>(
        H, W2s + (size_t)(l * 2 + 1) * HID * 1024, nullptr, YB, YB,
        M, HID, 1024);
    ln_kernel<<<M / 4, 256, 0, stream>>>(YB, ln2_w + l * HID, ln2_b + l * HID, X);
  };

  if (batched) {
    bf16* X   = (bf16*)p; p += T3 * HID * 2;
    bf16* BUF = (bf16*)p;
    bf16* QKV = BUF;
    bf16* ATT = BUF + T3 * QKV_D;
    bf16* H   = BUF;
    bf16* YB  = BUF + T3 * 1024;
    const int M = (int)T3;

    inproj_kernel<<<TOKENS * HID / 256, 256, 0, stream>>>(x, ip_w, ip_b, X, 3);
    for (int l = 0; l < 4; ++l)
      run_layer(l, M, X, QKV, ATT, YB, H, true, 0);
    for (int br = 0; br < 3; ++br)
      outdot_kernel<<<TOKENS / 4, 256, 0, stream>>>(
          X + (size_t)br * TOKENS * HID, op_w, ACC, br == 0);
  } else {
    // sequential (fits in ~79 MB)
    bf16* X   = (bf16*)p; p += (size_t)TOKENS * HID * 2;
    bf16* SCR = (bf16*)p; p += (size_t)TOKENS * FFN_D * 2;
    bf16* QKV = SCR;
    bf16* ATT = SCR + (size_t)TOKENS * QKV_D;
    bf16* H   = SCR;
    bf16* YB  = SCR + (size_t)TOKENS * 1024;
    const int M = TOKENS;

    for (int br = 0; br < 3; ++br) {
      inproj_kernel<<<TOKENS * HID / 256, 256, 0, stream>>>(x, ip_w, ip_b, X, 1);
      for (int l = 0; l < 4; ++l)
        run_layer(l, M, X, QKV, ATT, YB, H, false, br);
      outdot_kernel<<<TOKENS / 4, 256, 0, stream>>>(X, op_w, ACC, br == 0);
    }
  }
  pool_kernel<<<6, 256, 0, stream>>>(ACC, op_b, (float*)d_out);
}